// Round 9
// baseline (2605.080 us; speedup 1.0000x reference)
//
#include <hip/hip_runtime.h>

#define H 128
#define F_IN 16

typedef __attribute__((ext_vector_type(8))) short short8;
typedef __attribute__((ext_vector_type(4))) float f32x4;

// f32 -> bf16 round-to-nearest-even
__device__ __forceinline__ unsigned short f2bf(float f)
{
    unsigned u = __builtin_bit_cast(unsigned, f);
    u += 0x7FFFu + ((u >> 16) & 1u);
    return (unsigned short)(u >> 16);
}
__device__ __forceinline__ float bf2f(unsigned short h)
{
    return __builtin_bit_cast(float, (unsigned)h << 16);
}
struct BfPair { short hi, lo; };
// Split: x ≈ bf2f(hi) + bf2f(lo), residual ~2^-18 |x|
__device__ __forceinline__ BfPair split2(float x)
{
    BfPair p;
    unsigned short h = f2bf(x);
    p.hi = (short)h;
    p.lo = (short)f2bf(x - bf2f(h));
    return p;
}

// ---------------------------------------------------------------------------
// Stage a 64x128 f32 tile (rows r0..) as split bf16 into swizzled LDS, with
// optional fused BatchNorm. element (row,k) -> ushort idx row*128 + (k ^ ((row&7)<<3))
__device__ __forceinline__ void stage_split_bn(const float* __restrict__ src,
                                               unsigned short* sH, unsigned short* sL,
                                               int r0, int M, int t,
                                               const float* __restrict__ bnsums,
                                               const float* __restrict__ bng,
                                               const float* __restrict__ bnb,
                                               float invM)
{
#pragma unroll
    for (int i = 0; i < 4; ++i) {
        int cid  = t + 256 * i;
        int row  = cid >> 4;
        int ck   = cid & 15;
        int grow = r0 + row;
        short8 ph = (short8)0, pl = (short8)0;
        if (grow < M) {
            const float4* q = (const float4*)(src + (size_t)grow * H + ck * 8);
            float4 a = q[0], b = q[1];
            float xs[8] = {a.x, a.y, a.z, a.w, b.x, b.y, b.z, b.w};
            if (bnsums) {
                int j0 = ck * 8;
#pragma unroll
                for (int j = 0; j < 8; ++j) {
                    float mean = bnsums[j0 + j] * invM;
                    float var  = bnsums[H + j0 + j] * invM - mean * mean;
                    float s    = rsqrtf(var + 1e-5f) * bng[j0 + j];
                    xs[j] = (xs[j] - mean) * s + bnb[j0 + j];
                }
            }
#pragma unroll
            for (int j = 0; j < 8; ++j) {
                BfPair p = split2(xs[j]);
                ph[j] = p.hi;
                pl[j] = p.lo;
            }
        }
        int addr = (row << 7) + ((ck ^ (row & 7)) << 3);
        *(short8*)(sH + addr) = ph;
        *(short8*)(sL + addr) = pl;
    }
}

// value = aggsum[row][k] / max(cnt[row],1) (int counts)
__device__ __forceinline__ void stage_agg_split(const float* __restrict__ aggsum,
                                                const int* __restrict__ cnt,
                                                unsigned short* sH, unsigned short* sL,
                                                int r0, int M, int t)
{
#pragma unroll
    for (int i = 0; i < 4; ++i) {
        int cid  = t + 256 * i;
        int row  = cid >> 4;
        int ck   = cid & 15;
        int grow = r0 + row;
        short8 ph = (short8)0, pl = (short8)0;
        if (grow < M) {
            const float4* q = (const float4*)(aggsum + (size_t)grow * H + ck * 8);
            float4 a = q[0], b = q[1];
            int c = cnt[grow];
            float inv = 1.f / (float)(c > 1 ? c : 1);
            float xs[8] = {a.x * inv, a.y * inv, a.z * inv, a.w * inv,
                           b.x * inv, b.y * inv, b.z * inv, b.w * inv};
#pragma unroll
            for (int j = 0; j < 8; ++j) {
                BfPair p = split2(xs[j]);
                ph[j] = p.hi;
                pl[j] = p.lo;
            }
        }
        int addr = (row << 7) + ((ck ^ (row & 7)) << 3);
        *(short8*)(sH + addr) = ph;
        *(short8*)(sL + addr) = pl;
    }
}

// ---------------------------------------------------------------------------
// Preload split B-fragments of W (f32 [128][128]) covering cols jb..jb+31.
__device__ __forceinline__ void load_wfrag_split(const float* __restrict__ W, int jb,
                                                 int lane, short8 wfh[4][2], short8 wfl[4][2])
{
    const int g = lane >> 4, c0 = lane & 15;
#pragma unroll
    for (int s = 0; s < 4; ++s)
#pragma unroll
        for (int c = 0; c < 2; ++c) {
            short8 fh, fl;
#pragma unroll
            for (int j = 0; j < 8; ++j) {
                int k = 32 * s + 8 * g + j;
                BfPair p = split2(W[(size_t)k * H + jb + 16 * c + c0]);
                fh[j] = p.hi;
                fl[j] = p.lo;
            }
            wfh[s][c] = fh;
            wfl[s][c] = fl;
        }
}

// acc += (sH+sL) @ (Wh+Wl), 3 MFMA products per k-step (al@wl dropped)
__device__ __forceinline__ void mfma_gemm3(const unsigned short* sH, const unsigned short* sL,
                                           const short8 wfh[4][2], const short8 wfl[4][2],
                                           f32x4 acc[4][2], int lane)
{
    const int g = lane >> 4, r = lane & 15;
#pragma unroll
    for (int s = 0; s < 4; ++s) {
        short8 ah[4], al[4];
#pragma unroll
        for (int fr = 0; fr < 4; ++fr) {
            int row  = 16 * fr + r;
            int ck   = (4 * s + g) ^ (row & 7);
            int addr = (row << 7) + (ck << 3);
            ah[fr] = *(const short8*)(sH + addr);
            al[fr] = *(const short8*)(sL + addr);
        }
#pragma unroll
        for (int fr = 0; fr < 4; ++fr)
#pragma unroll
            for (int c = 0; c < 2; ++c) {
                f32x4 a = acc[fr][c];
                a = __builtin_amdgcn_mfma_f32_16x16x32_bf16(ah[fr], wfh[s][c], a, 0, 0, 0);
                a = __builtin_amdgcn_mfma_f32_16x16x32_bf16(al[fr], wfh[s][c], a, 0, 0, 0);
                a = __builtin_amdgcn_mfma_f32_16x16x32_bf16(ah[fr], wfl[s][c], a, 0, 0, 0);
                acc[fr][c] = a;
            }
    }
}

__device__ __forceinline__ void zero_acc(f32x4 acc[4][2])
{
#pragma unroll
    for (int fr = 0; fr < 4; ++fr)
#pragma unroll
        for (int c = 0; c < 2; ++c) {
            acc[fr][c][0] = 0.f; acc[fr][c][1] = 0.f;
            acc[fr][c][2] = 0.f; acc[fr][c][3] = 0.f;
        }
}

// ---------------------------------------------------------------------------
// One-time sort machinery (edge_index is layer-invariant)
__global__ __launch_bounds__(256) void hist_kernel(const int* __restrict__ col,
                                                   int* __restrict__ cnt, int E)
{
    int e = blockIdx.x * 256 + threadIdx.x;
    if (e < E) atomicAdd(&cnt[col[e]], 1);
}

// Single-block exclusive scan over Nn counts -> offs
__global__ __launch_bounds__(1024) void scan_kernel(const int* __restrict__ cnt,
                                                    int* __restrict__ offs, int Nn)
{
    __shared__ int ls[1024];
    int t = threadIdx.x;
    int per = (Nn + 1023) / 1024;
    int base = t * per;
    int s = 0;
    for (int k = 0; k < per; ++k) {
        int i = base + k;
        if (i < Nn) s += cnt[i];
    }
    ls[t] = s;
    __syncthreads();
    for (int d = 1; d < 1024; d <<= 1) {
        int u = (t >= d) ? ls[t - d] : 0;
        __syncthreads();
        ls[t] += u;
        __syncthreads();
    }
    int run = ls[t] - s;
    for (int k = 0; k < per; ++k) {
        int i = base + k;
        if (i < Nn) {
            offs[i] = run;
            run += cnt[i];
        }
    }
}

// scatter + build permuted index arrays
__global__ __launch_bounds__(256) void scatter_kernel(const int* __restrict__ row,
                                                      const int* __restrict__ col,
                                                      const int* __restrict__ offs,
                                                      int* __restrict__ tmpc,
                                                      int* __restrict__ sortedIds,
                                                      int* __restrict__ rowS,
                                                      int* __restrict__ colS, int E)
{
    int e = blockIdx.x * 256 + threadIdx.x;
    if (e < E) {
        int c = col[e];
        int p = offs[c] + atomicAdd(&tmpc[c], 1);
        sortedIds[p] = e;
        rowS[p] = row[e];
        colS[p] = c;
    }
}

// ---------------------------------------------------------------------------
// Encoder: out = relu(X[M,16] @ W[16,128] + b)
__global__ __launch_bounds__(256) void enc_kernel(const float* __restrict__ X,
                                                  const float* __restrict__ W,
                                                  const float* __restrict__ bias,
                                                  float* __restrict__ out, int M)
{
    __shared__ float sW[F_IN * H];
    __shared__ float sb[H];
    int t = threadIdx.x;
    reinterpret_cast<float4*>(sW)[t]       = reinterpret_cast<const float4*>(W)[t];
    reinterpret_cast<float4*>(sW)[t + 256] = reinterpret_cast<const float4*>(W)[t + 256];
    if (t < H) sb[t] = bias[t];
    __syncthreads();
    int row = blockIdx.x * 2 + (t >> 7);
    if (row >= M) return;
    int j = t & 127;
    float acc = sb[j];
#pragma unroll
    for (int k = 0; k < F_IN; ++k)
        acc += X[(size_t)row * F_IN + k] * sW[k * H + j];
    out[(size_t)row * H + j] = fmaxf(acc, 0.f);
}

// Gather-encoder: out[p] = relu(X[sortedIds[p],16] @ W + b)  (one-time)
__global__ __launch_bounds__(256) void enc_gather_kernel(const float* __restrict__ X,
                                                         const int* __restrict__ sortedIds,
                                                         const float* __restrict__ W,
                                                         const float* __restrict__ bias,
                                                         float* __restrict__ out, int M)
{
    __shared__ float sW[F_IN * H];
    __shared__ float sb[H];
    int t = threadIdx.x;
    reinterpret_cast<float4*>(sW)[t]       = reinterpret_cast<const float4*>(W)[t];
    reinterpret_cast<float4*>(sW)[t + 256] = reinterpret_cast<const float4*>(W)[t + 256];
    if (t < H) sb[t] = bias[t];
    __syncthreads();
    int p = blockIdx.x * 2 + (t >> 7);
    if (p >= M) return;
    int src = sortedIds[p];
    int j = t & 127;
    float acc = sb[j];
#pragma unroll
    for (int k = 0; k < F_IN; ++k)
        acc += X[(size_t)src * F_IN + k] * sW[k * H + j];
    out[(size_t)p * H + j] = fmaxf(acc, 0.f);
}

// ---------------------------------------------------------------------------
// ABP: A = bn(h)@W1, B = bn(h)@W2, P = bn(h)@U1 (raw outputs).
__global__ __launch_bounds__(256, 5) void abp_kernel(const float* __restrict__ hb,
                                                     const float* __restrict__ eW,
                                                     const float* __restrict__ n1W,
                                                     float* __restrict__ Aout,
                                                     float* __restrict__ Bout,
                                                     float* __restrict__ Pout, int M,
                                                     const float* __restrict__ bnsums,
                                                     const float* __restrict__ bng,
                                                     const float* __restrict__ bnb,
                                                     float invM)
{
    __shared__ __align__(16) unsigned short sAh[64 * 128];
    __shared__ __align__(16) unsigned short sAl[64 * 128];
    const int t = threadIdx.x, lane = t & 63, w = t >> 6, jb = 32 * w;
    const int r0 = blockIdx.x * 64;
    stage_split_bn(hb, sAh, sAl, r0, M, t, bnsums, bng, bnb, invM);
    __syncthreads();
    const int g = lane >> 4, c0 = lane & 15;
    short8 wfh[4][2], wfl[4][2];
    f32x4  acc[4][2];
#pragma unroll
    for (int p = 0; p < 3; ++p) {
        const float* W = (p == 0) ? eW : (p == 1) ? eW + H * H : n1W;
        float* C       = (p == 0) ? Aout : (p == 1) ? Bout : Pout;
        load_wfrag_split(W, jb, lane, wfh, wfl);
        zero_acc(acc);
        mfma_gemm3(sAh, sAl, wfh, wfl, acc, lane);
#pragma unroll
        for (int fr = 0; fr < 4; ++fr)
#pragma unroll
            for (int c = 0; c < 2; ++c) {
                int j = jb + 16 * c + c0;
#pragma unroll
                for (int r = 0; r < 4; ++r) {
                    int row = r0 + 16 * fr + 4 * g + r;
                    if (row < M) C[(size_t)row * H + j] = acc[fr][c][r];
                }
            }
    }
}

// ---------------------------------------------------------------------------
// Fused edge kernel over col-sorted e layout (stream in, stream out):
//   e'[p] = relu(bn(e[p])@W3 + A[rowS[p]] + B[colS[p]] + be)
//   m     = relu(e'@U2 + P[rowS[p]] + b1)
//   aggsum[col] += segment-reduced m  (LDS reduction, ~1 atomic per distinct col)
//   fused e'-stats -> eStats
__global__ __launch_bounds__(256, 4) void edge_kernel(float* eb,
                                                      const int* __restrict__ rowS,
                                                      const int* __restrict__ colS,
                                                      const float* __restrict__ Asrc,
                                                      const float* __restrict__ Bsrc,
                                                      const float* __restrict__ Psrc,
                                                      const float* __restrict__ W3,
                                                      const float* __restrict__ U2,
                                                      const float* __restrict__ be,
                                                      const float* __restrict__ b1,
                                                      float* __restrict__ aggsum, int E,
                                                      const float* __restrict__ bnsums,
                                                      const float* __restrict__ bng,
                                                      const float* __restrict__ bnb,
                                                      float invE,
                                                      float* __restrict__ eStats)
{
    __shared__ __align__(16) unsigned char smem[64 * 128 * 4 + 256];
    unsigned short* sAh = (unsigned short*)smem;            // 16 KB
    unsigned short* sAl = sAh + 64 * 128;                   // 16 KB
    float*          mbuf = (float*)smem;                    // 32 KB (reuses both)
    int*            scol = (int*)(smem + 64 * 128 * 4);     // 256 B

    const int t = threadIdx.x, lane = t & 63, w = t >> 6, jb = 32 * w;
    const int e0 = blockIdx.x * 64;
    const int g = lane >> 4, c0 = lane & 15;
    stage_split_bn(eb, sAh, sAl, e0, E, t, bnsums, bng, bnb, invE);
    if (t < 64) scol[t] = colS[(e0 + t < E) ? (e0 + t) : (E - 1)];

    // permuted indices for this lane's 16 rows
    int ridx[4][4], cidx[4][4];
#pragma unroll
    for (int fr = 0; fr < 4; ++fr)
#pragma unroll
        for (int r = 0; r < 4; ++r) {
            int p  = e0 + 16 * fr + 4 * g + r;
            int pc = (p < E) ? p : (E - 1);
            ridx[fr][r] = rowS[pc];
            cidx[fr][r] = colS[pc];
        }
    (void)cidx;

    short8 wfh[4][2], wfl[4][2];
    load_wfrag_split(W3, jb, lane, wfh, wfl);
    f32x4 acc[4][2];
    zero_acc(acc);
    __syncthreads();
    mfma_gemm3(sAh, sAl, wfh, wfl, acc, lane);
    __syncthreads();   // all LDS reads of the e-tile done

    // epilogue 1: e' -> global (streaming by p), split(e') back into same LDS
    float s1[2] = {0.f, 0.f}, s2[2] = {0.f, 0.f};
#pragma unroll
    for (int fr = 0; fr < 4; ++fr)
#pragma unroll
        for (int c = 0; c < 2; ++c) {
            int j = jb + 16 * c + c0;
            float bej = be[j];
#pragma unroll
            for (int r = 0; r < 4; ++r) {
                int Rl = 16 * fr + 4 * g + r;
                int p  = e0 + Rl;
                float v = acc[fr][c][r]
                        + Asrc[(size_t)ridx[fr][r] * H + j]
                        + Bsrc[(size_t)scol[Rl] * H + j] + bej;
                v = fmaxf(v, 0.f);
                if (p < E) {
                    eb[(size_t)p * H + j] = v;
                    s1[c] += v;
                    s2[c] += v * v;
                }
                int addr = (Rl << 7) + (j ^ ((Rl & 7) << 3));
                BfPair pp = split2(v);
                sAh[addr] = (unsigned short)pp.hi;
                sAl[addr] = (unsigned short)pp.lo;
            }
        }
    __syncthreads();

    load_wfrag_split(U2, jb, lane, wfh, wfl);
    zero_acc(acc);
    mfma_gemm3(sAh, sAl, wfh, wfl, acc, lane);
    __syncthreads();   // all waves done reading sA -> safe to overwrite with mbuf

    // epilogue 2: m -> mbuf (bank-swizzled so 4 g-groups hit distinct banks)
#pragma unroll
    for (int fr = 0; fr < 4; ++fr)
#pragma unroll
        for (int c = 0; c < 2; ++c) {
            int j = jb + 16 * c + c0;
            float b1j = b1[j];
#pragma unroll
            for (int r = 0; r < 4; ++r) {
                int Rl = 16 * fr + 4 * g + r;
                float v = fmaxf(acc[fr][c][r] + Psrc[(size_t)ridx[fr][r] * H + j] + b1j, 0.f);
                mbuf[(Rl << 7) + (j ^ (((Rl >> 2) & 3) << 3))] = v;
            }
        }
    __syncthreads();

    // segmented reduction: thread j walks 64 sorted rows, 1 atomic per segment
    if (t < 128) {
        int j = t;
        float run = 0.f;
        int cur = scol[0];
        for (int row = 0; row < 64; ++row) {
            int cc = scol[row];
            float v = mbuf[(row << 7) + (j ^ (((row >> 2) & 3) << 3))];
            if (cc != cur) {
                atomicAdd(&aggsum[(size_t)cur * H + j], run);
                run = 0.f;
                cur = cc;
            }
            if (e0 + row < E) run += v;
        }
        atomicAdd(&aggsum[(size_t)cur * H + j], run);
    }

    // fused e'-stats: reduce over the 4 row-groups, then one atomic per (j, kind)
#pragma unroll
    for (int c = 0; c < 2; ++c) {
        float a = s1[c], b = s2[c];
        a += __shfl_xor(a, 16); a += __shfl_xor(a, 32);
        b += __shfl_xor(b, 16); b += __shfl_xor(b, 32);
        if (g == 0) {
            int j = jb + 16 * c + c0;
            atomicAdd(&eStats[j], a);
            atomicAdd(&eStats[H + j], b);
        }
    }
}

// ---------------------------------------------------------------------------
// Node update (in place): h = relu(bn(h)@V1 + (aggsum/max(cnt,1))@V2 + b2)
// fused h-stats -> hStats
__global__ __launch_bounds__(256, 5) void node_kernel(float* hb,
                                                      const float* __restrict__ aggsum,
                                                      const int* __restrict__ cnt,
                                                      const float* __restrict__ V,
                                                      const float* __restrict__ b2, int M,
                                                      const float* __restrict__ bnsums,
                                                      const float* __restrict__ bng,
                                                      const float* __restrict__ bnb,
                                                      float invM,
                                                      float* __restrict__ hStats)
{
    __shared__ __align__(16) unsigned short sAh[64 * 128];
    __shared__ __align__(16) unsigned short sAl[64 * 128];
    const int t = threadIdx.x, lane = t & 63, w = t >> 6, jb = 32 * w;
    const int r0 = blockIdx.x * 64;
    stage_split_bn(hb, sAh, sAl, r0, M, t, bnsums, bng, bnb, invM);
    short8 wfh[4][2], wfl[4][2];
    load_wfrag_split(V, jb, lane, wfh, wfl);
    f32x4 acc[4][2];
    zero_acc(acc);
    __syncthreads();
    mfma_gemm3(sAh, sAl, wfh, wfl, acc, lane);
    __syncthreads();   // h-tile reads done
    stage_agg_split(aggsum, cnt, sAh, sAl, r0, M, t);
    load_wfrag_split(V + H * H, jb, lane, wfh, wfl);
    __syncthreads();
    mfma_gemm3(sAh, sAl, wfh, wfl, acc, lane);
    const int g = lane >> 4, c0 = lane & 15;
    float s1[2] = {0.f, 0.f}, s2[2] = {0.f, 0.f};
#pragma unroll
    for (int fr = 0; fr < 4; ++fr)
#pragma unroll
        for (int c = 0; c < 2; ++c) {
            int j = jb + 16 * c + c0;
            float bj = b2[j];
#pragma unroll
            for (int r = 0; r < 4; ++r) {
                int row = r0 + 16 * fr + 4 * g + r;
                if (row < M) {
                    float v = fmaxf(acc[fr][c][r] + bj, 0.f);
                    hb[(size_t)row * H + j] = v;
                    s1[c] += v;
                    s2[c] += v * v;
                }
            }
        }
#pragma unroll
    for (int c = 0; c < 2; ++c) {
        float a = s1[c], b = s2[c];
        a += __shfl_xor(a, 16); a += __shfl_xor(a, 32);
        b += __shfl_xor(b, 16); b += __shfl_xor(b, 32);
        if (g == 0) {
            int j = jb + 16 * c + c0;
            atomicAdd(&hStats[j], a);
            atomicAdd(&hStats[H + j], b);
        }
    }
}

// ---------------------------------------------------------------------------
// Final readout: out = [mean(h) | mean(e)] @ reg_w + reg_b
__global__ __launch_bounds__(256) void final_kernel(const float* __restrict__ hsum,
                                                    const float* __restrict__ esum,
                                                    const float* __restrict__ reg_w,
                                                    const float* __restrict__ reg_b,
                                                    float* __restrict__ out,
                                                    float invN, float invE)
{
    __shared__ float red[256];
    int t = threadIdx.x;
    float v = (t < 128) ? hsum[t] * invN * reg_w[t]
                        : esum[t - 128] * invE * reg_w[t];
    red[t] = v;
    __syncthreads();
    for (int s = 128; s > 0; s >>= 1) {
        if (t < s) red[t] += red[t + s];
        __syncthreads();
    }
    if (t == 0) out[0] = red[0] + reg_b[0];
}

// ---------------------------------------------------------------------------
extern "C" void kernel_launch(void* const* d_in, const int* in_sizes, int n_in,
                              void* d_out, int out_size, void* d_ws, size_t ws_size,
                              hipStream_t stream)
{
    const float* x          = (const float*)d_in[0];
    const int*   edge_index = (const int*)  d_in[1];
    const float* edge_attr  = (const float*)d_in[2];
    const float* enc_node_w = (const float*)d_in[3];
    const float* enc_node_b = (const float*)d_in[4];
    const float* enc_edge_w = (const float*)d_in[5];
    const float* enc_edge_b = (const float*)d_in[6];
    const float* edge_w     = (const float*)d_in[7];
    const float* edge_b     = (const float*)d_in[8];
    const float* n1_w       = (const float*)d_in[9];
    const float* n1_b       = (const float*)d_in[10];
    const float* n2_w       = (const float*)d_in[11];
    const float* n2_b       = (const float*)d_in[12];
    const float* bn_node_g  = (const float*)d_in[13];
    const float* bn_node_b  = (const float*)d_in[14];
    const float* bn_edge_g  = (const float*)d_in[15];
    const float* bn_edge_b  = (const float*)d_in[16];
    const float* reg_w      = (const float*)d_in[17];
    const float* reg_b      = (const float*)d_in[18];

    const int N = in_sizes[0] / F_IN;
    const int E = in_sizes[1] / 2;
    const size_t NH = (size_t)N * H;
    const size_t EH = (size_t)E * H;

    float* ws     = (float*)d_ws;
    float* hbuf   = ws;                 // [N,128]
    float* ebuf   = hbuf + NH;          // [E,128]  (stored in col-sorted order)
    float* Abuf   = ebuf + EH;          // [N,128]
    float* Bbuf   = Abuf + NH;          // [N,128]
    float* Pbuf   = Bbuf + NH;          // [N,128]
    float* aggsum = Pbuf + NH;          // [N,128]
    float* statsA = aggsum + NH;        // 512
    float* statsB = statsA + 512;       // 512
    int*   cnt_i  = (int*)(statsB + 512);   // [N]
    int*   tmpc   = cnt_i + N;              // [N]
    int*   offs   = tmpc + N;               // [N+1]
    int*   sortedIds = offs + N + 1;        // [E]
    int*   rowS   = sortedIds + E;          // [E]
    int*   colS   = rowS + E;               // [E]

    const int* row_idx = edge_index;
    const int* col_idx = edge_index + E;
    const float invN = 1.f / (float)N;
    const float invE = 1.f / (float)E;

    // one-time: sort edges by col, build permuted index arrays
    (void)hipMemsetAsync(cnt_i, 0, (size_t)2 * N * sizeof(int), stream);
    hist_kernel<<<(E + 255) / 256, 256, 0, stream>>>(col_idx, cnt_i, E);
    scan_kernel<<<1, 1024, 0, stream>>>(cnt_i, offs, N);
    scatter_kernel<<<(E + 255) / 256, 256, 0, stream>>>(row_idx, col_idx, offs, tmpc,
                                                        sortedIds, rowS, colS, E);

    enc_kernel<<<(N + 1) / 2, 256, 0, stream>>>(x, enc_node_w, enc_node_b, hbuf, N);
    enc_gather_kernel<<<(E + 1) / 2, 256, 0, stream>>>(edge_attr, sortedIds,
                                                       enc_edge_w, enc_edge_b, ebuf, E);

    const int nodeBlocks = (N + 63) / 64;
    const int edgeBlocks = (E + 63) / 64;

    for (int i = 0; i < 3; ++i) {
        float*       Scur  = (i & 1) ? statsB : statsA;
        const float* Sprev = (i == 0) ? nullptr : ((i & 1) ? statsA : statsB);
        (void)hipMemsetAsync(aggsum, 0, NH * sizeof(float), stream);
        (void)hipMemsetAsync(Scur, 0, 512 * sizeof(float), stream);
        abp_kernel<<<nodeBlocks, 256, 0, stream>>>(
            hbuf, edge_w + (size_t)i * 384 * H, n1_w + (size_t)i * 256 * H,
            Abuf, Bbuf, Pbuf, N,
            Sprev, bn_node_g, bn_node_b, invN);
        edge_kernel<<<edgeBlocks, 256, 0, stream>>>(
            ebuf, rowS, colS, Abuf, Bbuf, Pbuf,
            edge_w + (size_t)i * 384 * H + 256 * H,
            n1_w + (size_t)i * 256 * H + 128 * H,
            edge_b + i * H, n1_b + i * H,
            aggsum, E,
            Sprev ? Sprev + 256 : nullptr, bn_edge_g, bn_edge_b, invE,
            Scur + 256);
        node_kernel<<<nodeBlocks, 256, 0, stream>>>(
            hbuf, aggsum, cnt_i, n2_w + (size_t)i * 256 * H, n2_b + i * H, N,
            Sprev, bn_node_g, bn_node_b, invN,
            Scur);
    }
    // i=2 wrote statsA
    final_kernel<<<1, 256, 0, stream>>>(statsA, statsA + 256, reg_w, reg_b,
                                        (float*)d_out, invN, invE);
}

// Round 10
// 1282.004 us; speedup vs baseline: 2.0320x; 2.0320x over previous
//
#include <hip/hip_runtime.h>

#define H 128
#define F_IN 16

typedef __attribute__((ext_vector_type(8))) short short8;
typedef __attribute__((ext_vector_type(4))) float f32x4;

// f32 -> bf16 round-to-nearest-even
__device__ __forceinline__ unsigned short f2bf(float f)
{
    unsigned u = __builtin_bit_cast(unsigned, f);
    u += 0x7FFFu + ((u >> 16) & 1u);
    return (unsigned short)(u >> 16);
}
__device__ __forceinline__ float bf2f(unsigned short h)
{
    return __builtin_bit_cast(float, (unsigned)h << 16);
}
struct BfPair { short hi, lo; };
// Split: x ≈ bf2f(hi) + bf2f(lo), residual ~2^-18 |x|
__device__ __forceinline__ BfPair split2(float x)
{
    BfPair p;
    unsigned short h = f2bf(x);
    p.hi = (short)h;
    p.lo = (short)f2bf(x - bf2f(h));
    return p;
}

// ---------------------------------------------------------------------------
// Stage a 64x128 f32 tile (rows r0..) as split bf16 into swizzled LDS, with
// optional fused BatchNorm. element (row,k) -> ushort idx row*128 + (k ^ ((row&7)<<3))
__device__ __forceinline__ void stage_split_bn(const float* __restrict__ src,
                                               unsigned short* sH, unsigned short* sL,
                                               int r0, int M, int t,
                                               const float* __restrict__ bnsums,
                                               const float* __restrict__ bng,
                                               const float* __restrict__ bnb,
                                               float invM)
{
#pragma unroll
    for (int i = 0; i < 4; ++i) {
        int cid  = t + 256 * i;
        int row  = cid >> 4;
        int ck   = cid & 15;
        int grow = r0 + row;
        short8 ph = (short8)0, pl = (short8)0;
        if (grow < M) {
            const float4* q = (const float4*)(src + (size_t)grow * H + ck * 8);
            float4 a = q[0], b = q[1];
            float xs[8] = {a.x, a.y, a.z, a.w, b.x, b.y, b.z, b.w};
            if (bnsums) {
                int j0 = ck * 8;
#pragma unroll
                for (int j = 0; j < 8; ++j) {
                    float mean = bnsums[j0 + j] * invM;
                    float var  = bnsums[H + j0 + j] * invM - mean * mean;
                    float s    = rsqrtf(var + 1e-5f) * bng[j0 + j];
                    xs[j] = (xs[j] - mean) * s + bnb[j0 + j];
                }
            }
#pragma unroll
            for (int j = 0; j < 8; ++j) {
                BfPair p = split2(xs[j]);
                ph[j] = p.hi;
                pl[j] = p.lo;
            }
        }
        int addr = (row << 7) + ((ck ^ (row & 7)) << 3);
        *(short8*)(sH + addr) = ph;
        *(short8*)(sL + addr) = pl;
    }
}

// Gather variant: tile row i holds src[idx[p0+i]], with fused BN.
__device__ __forceinline__ void stage_split_bn_gather(const float* __restrict__ src,
                                                      const int* __restrict__ idx,
                                                      unsigned short* sH, unsigned short* sL,
                                                      int p0, int M, int t,
                                                      const float* __restrict__ bnsums,
                                                      const float* __restrict__ bng,
                                                      const float* __restrict__ bnb,
                                                      float invM)
{
#pragma unroll
    for (int i = 0; i < 4; ++i) {
        int cid = t + 256 * i;
        int row = cid >> 4;
        int ck  = cid & 15;
        int p   = p0 + row;
        short8 ph = (short8)0, pl = (short8)0;
        if (p < M) {
            int srcRow = idx[p];
            const float4* q = (const float4*)(src + (size_t)srcRow * H + ck * 8);
            float4 a = q[0], b = q[1];
            float xs[8] = {a.x, a.y, a.z, a.w, b.x, b.y, b.z, b.w};
            if (bnsums) {
                int j0 = ck * 8;
#pragma unroll
                for (int j = 0; j < 8; ++j) {
                    float mean = bnsums[j0 + j] * invM;
                    float var  = bnsums[H + j0 + j] * invM - mean * mean;
                    float s    = rsqrtf(var + 1e-5f) * bng[j0 + j];
                    xs[j] = (xs[j] - mean) * s + bnb[j0 + j];
                }
            }
#pragma unroll
            for (int j = 0; j < 8; ++j) {
                BfPair pp = split2(xs[j]);
                ph[j] = pp.hi;
                pl[j] = pp.lo;
            }
        }
        int addr = (row << 7) + ((ck ^ (row & 7)) << 3);
        *(short8*)(sH + addr) = ph;
        *(short8*)(sL + addr) = pl;
    }
}

// value = aggsum[row][k] / max(cnt[row],1) (int counts)
__device__ __forceinline__ void stage_agg_split(const float* __restrict__ aggsum,
                                                const int* __restrict__ cnt,
                                                unsigned short* sH, unsigned short* sL,
                                                int r0, int M, int t)
{
#pragma unroll
    for (int i = 0; i < 4; ++i) {
        int cid  = t + 256 * i;
        int row  = cid >> 4;
        int ck   = cid & 15;
        int grow = r0 + row;
        short8 ph = (short8)0, pl = (short8)0;
        if (grow < M) {
            const float4* q = (const float4*)(aggsum + (size_t)grow * H + ck * 8);
            float4 a = q[0], b = q[1];
            int c = cnt[grow];
            float inv = 1.f / (float)(c > 1 ? c : 1);
            float xs[8] = {a.x * inv, a.y * inv, a.z * inv, a.w * inv,
                           b.x * inv, b.y * inv, b.z * inv, b.w * inv};
#pragma unroll
            for (int j = 0; j < 8; ++j) {
                BfPair p = split2(xs[j]);
                ph[j] = p.hi;
                pl[j] = p.lo;
            }
        }
        int addr = (row << 7) + ((ck ^ (row & 7)) << 3);
        *(short8*)(sH + addr) = ph;
        *(short8*)(sL + addr) = pl;
    }
}

// ---------------------------------------------------------------------------
// Preload split B-fragments of W (f32 [128][128]) covering cols jb..jb+31.
__device__ __forceinline__ void load_wfrag_split(const float* __restrict__ W, int jb,
                                                 int lane, short8 wfh[4][2], short8 wfl[4][2])
{
    const int g = lane >> 4, c0 = lane & 15;
#pragma unroll
    for (int s = 0; s < 4; ++s)
#pragma unroll
        for (int c = 0; c < 2; ++c) {
            short8 fh, fl;
#pragma unroll
            for (int j = 0; j < 8; ++j) {
                int k = 32 * s + 8 * g + j;
                BfPair p = split2(W[(size_t)k * H + jb + 16 * c + c0]);
                fh[j] = p.hi;
                fl[j] = p.lo;
            }
            wfh[s][c] = fh;
            wfl[s][c] = fl;
        }
}

// acc += (sH+sL) @ (Wh+Wl), 3 MFMA products per k-step (al@wl dropped)
__device__ __forceinline__ void mfma_gemm3(const unsigned short* sH, const unsigned short* sL,
                                           const short8 wfh[4][2], const short8 wfl[4][2],
                                           f32x4 acc[4][2], int lane)
{
    const int g = lane >> 4, r = lane & 15;
#pragma unroll
    for (int s = 0; s < 4; ++s) {
        short8 ah[4], al[4];
#pragma unroll
        for (int fr = 0; fr < 4; ++fr) {
            int row  = 16 * fr + r;
            int ck   = (4 * s + g) ^ (row & 7);
            int addr = (row << 7) + (ck << 3);
            ah[fr] = *(const short8*)(sH + addr);
            al[fr] = *(const short8*)(sL + addr);
        }
#pragma unroll
        for (int fr = 0; fr < 4; ++fr)
#pragma unroll
            for (int c = 0; c < 2; ++c) {
                f32x4 a = acc[fr][c];
                a = __builtin_amdgcn_mfma_f32_16x16x32_bf16(ah[fr], wfh[s][c], a, 0, 0, 0);
                a = __builtin_amdgcn_mfma_f32_16x16x32_bf16(al[fr], wfh[s][c], a, 0, 0, 0);
                a = __builtin_amdgcn_mfma_f32_16x16x32_bf16(ah[fr], wfl[s][c], a, 0, 0, 0);
                acc[fr][c] = a;
            }
    }
}

__device__ __forceinline__ void zero_acc(f32x4 acc[4][2])
{
#pragma unroll
    for (int fr = 0; fr < 4; ++fr)
#pragma unroll
        for (int c = 0; c < 2; ++c) {
            acc[fr][c][0] = 0.f; acc[fr][c][1] = 0.f;
            acc[fr][c][2] = 0.f; acc[fr][c][3] = 0.f;
        }
}

// ---------------------------------------------------------------------------
// One-time sort machinery (edge_index is layer-invariant)
__global__ __launch_bounds__(256) void hist_kernel(const int* __restrict__ col,
                                                   int* __restrict__ cnt, int E)
{
    int e = blockIdx.x * 256 + threadIdx.x;
    if (e < E) atomicAdd(&cnt[col[e]], 1);
}

__global__ __launch_bounds__(1024) void scan_kernel(const int* __restrict__ cnt,
                                                    int* __restrict__ offs, int Nn)
{
    __shared__ int ls[1024];
    int t = threadIdx.x;
    int per = (Nn + 1023) / 1024;
    int base = t * per;
    int s = 0;
    for (int k = 0; k < per; ++k) {
        int i = base + k;
        if (i < Nn) s += cnt[i];
    }
    ls[t] = s;
    __syncthreads();
    for (int d = 1; d < 1024; d <<= 1) {
        int u = (t >= d) ? ls[t - d] : 0;
        __syncthreads();
        ls[t] += u;
        __syncthreads();
    }
    int run = ls[t] - s;
    for (int k = 0; k < per; ++k) {
        int i = base + k;
        if (i < Nn) {
            offs[i] = run;
            run += cnt[i];
        }
    }
}

__global__ __launch_bounds__(256) void scatter_kernel(const int* __restrict__ row,
                                                      const int* __restrict__ col,
                                                      const int* __restrict__ offs,
                                                      int* __restrict__ tmpc,
                                                      int* __restrict__ sortedIds,
                                                      int* __restrict__ rowS,
                                                      int* __restrict__ colS, int E)
{
    int e = blockIdx.x * 256 + threadIdx.x;
    if (e < E) {
        int c = col[e];
        int p = offs[c] + atomicAdd(&tmpc[c], 1);
        sortedIds[p] = e;
        rowS[p] = row[e];
        colS[p] = c;
    }
}

// ---------------------------------------------------------------------------
// Encoder: out = relu(X[M,16] @ W[16,128] + b)
__global__ __launch_bounds__(256) void enc_kernel(const float* __restrict__ X,
                                                  const float* __restrict__ W,
                                                  const float* __restrict__ bias,
                                                  float* __restrict__ out, int M)
{
    __shared__ float sW[F_IN * H];
    __shared__ float sb[H];
    int t = threadIdx.x;
    reinterpret_cast<float4*>(sW)[t]       = reinterpret_cast<const float4*>(W)[t];
    reinterpret_cast<float4*>(sW)[t + 256] = reinterpret_cast<const float4*>(W)[t + 256];
    if (t < H) sb[t] = bias[t];
    __syncthreads();
    int row = blockIdx.x * 2 + (t >> 7);
    if (row >= M) return;
    int j = t & 127;
    float acc = sb[j];
#pragma unroll
    for (int k = 0; k < F_IN; ++k)
        acc += X[(size_t)row * F_IN + k] * sW[k * H + j];
    out[(size_t)row * H + j] = fmaxf(acc, 0.f);
}

// Gather-encoder: out[p] = relu(X[sortedIds[p],16] @ W + b)  (one-time)
__global__ __launch_bounds__(256) void enc_gather_kernel(const float* __restrict__ X,
                                                         const int* __restrict__ sortedIds,
                                                         const float* __restrict__ W,
                                                         const float* __restrict__ bias,
                                                         float* __restrict__ out, int M)
{
    __shared__ float sW[F_IN * H];
    __shared__ float sb[H];
    int t = threadIdx.x;
    reinterpret_cast<float4*>(sW)[t]       = reinterpret_cast<const float4*>(W)[t];
    reinterpret_cast<float4*>(sW)[t + 256] = reinterpret_cast<const float4*>(W)[t + 256];
    if (t < H) sb[t] = bias[t];
    __syncthreads();
    int p = blockIdx.x * 2 + (t >> 7);
    if (p >= M) return;
    int src = sortedIds[p];
    int j = t & 127;
    float acc = sb[j];
#pragma unroll
    for (int k = 0; k < F_IN; ++k)
        acc += X[(size_t)src * F_IN + k] * sW[k * H + j];
    out[(size_t)p * H + j] = fmaxf(acc, 0.f);
}

// ---------------------------------------------------------------------------
// B-only precompute: B = bn(h)@W2 (raw output).
__global__ __launch_bounds__(256, 4) void bk_kernel(const float* __restrict__ hb,
                                                    const float* __restrict__ W2,
                                                    float* __restrict__ Bout, int M,
                                                    const float* __restrict__ bnsums,
                                                    const float* __restrict__ bng,
                                                    const float* __restrict__ bnb,
                                                    float invM)
{
    __shared__ __align__(16) unsigned short sAh[64 * 128];
    __shared__ __align__(16) unsigned short sAl[64 * 128];
    const int t = threadIdx.x, lane = t & 63, w = t >> 6, jb = 32 * w;
    const int r0 = blockIdx.x * 64;
    stage_split_bn(hb, sAh, sAl, r0, M, t, bnsums, bng, bnb, invM);
    const int g = lane >> 4, c0 = lane & 15;
    short8 wfh[4][2], wfl[4][2];
    load_wfrag_split(W2, jb, lane, wfh, wfl);
    f32x4 acc[4][2];
    zero_acc(acc);
    __syncthreads();
    mfma_gemm3(sAh, sAl, wfh, wfl, acc, lane);
#pragma unroll
    for (int fr = 0; fr < 4; ++fr)
#pragma unroll
        for (int c = 0; c < 2; ++c) {
            int j = jb + 16 * c + c0;
#pragma unroll
            for (int r = 0; r < 4; ++r) {
                int row = r0 + 16 * fr + 4 * g + r;
                if (row < M) Bout[(size_t)row * H + j] = acc[fr][c][r];
            }
        }
}

// ---------------------------------------------------------------------------
// Fused edge kernel over col-sorted e layout. Gathers bn(h)[row] ONCE into LDS
// and folds the old A/P terms into the MFMA phases:
//   e'[p] = relu(bn(e[p])@W3 + bn(h)[rowS]@W1 + B[colS] + be)
//   m     = relu(e'@U2 + bn(h)[rowS]@U1 + b1)
//   aggsum[col] += segment-reduced m ; fused e'-stats
__global__ __launch_bounds__(256, 2) void edge_kernel(float* eb,
                                                      const int* __restrict__ rowS,
                                                      const int* __restrict__ colS,
                                                      const float* __restrict__ hb,
                                                      const float* __restrict__ Bsrc,
                                                      const float* __restrict__ Wedge,  // W1 | W2 | W3
                                                      const float* __restrict__ Wn1,    // U1 | U2
                                                      const float* __restrict__ be,
                                                      const float* __restrict__ b1,
                                                      float* __restrict__ aggsum, int E,
                                                      const float* __restrict__ bnsumsE,
                                                      const float* __restrict__ bngE,
                                                      const float* __restrict__ bnbE,
                                                      float invE,
                                                      const float* __restrict__ bnsumsH,
                                                      const float* __restrict__ bngH,
                                                      const float* __restrict__ bnbH,
                                                      float invN,
                                                      float* __restrict__ eStats)
{
    __shared__ __align__(16) unsigned char smem[64 * 128 * 8 + 256];
    unsigned short* sEh = (unsigned short*)smem;          // 16 KB  e  (hi)
    unsigned short* sEl = sEh + 64 * 128;                 // 16 KB  e  (lo)
    unsigned short* sHh = sEl + 64 * 128;                 // 16 KB  h[row] (hi)
    unsigned short* sHl = sHh + 64 * 128;                 // 16 KB  h[row] (lo)
    float*          mbuf = (float*)smem;                  // 32 KB overlay on sE pair
    int*            scol = (int*)(smem + 64 * 128 * 8);   // 256 B

    const int t = threadIdx.x, lane = t & 63, w = t >> 6, jb = 32 * w;
    const int e0 = blockIdx.x * 64;
    const int g = lane >> 4, c0 = lane & 15;

    if (t < 64) scol[t] = colS[(e0 + t < E) ? (e0 + t) : (E - 1)];

    // per-lane col indices + early B prefetch (in flight across staging + GEMM1)
    int cidx[4][4];
#pragma unroll
    for (int fr = 0; fr < 4; ++fr)
#pragma unroll
        for (int r = 0; r < 4; ++r) {
            int p  = e0 + 16 * fr + 4 * g + r;
            int pc = (p < E) ? p : (E - 1);
            cidx[fr][r] = colS[pc];
        }
    float bPre[4][2][4];
#pragma unroll
    for (int fr = 0; fr < 4; ++fr)
#pragma unroll
        for (int c = 0; c < 2; ++c)
#pragma unroll
            for (int r = 0; r < 4; ++r)
                bPre[fr][c][r] = Bsrc[(size_t)cidx[fr][r] * H + jb + 16 * c + c0];

    // stage e tile (BN_e fused) + gathered h[row] tile (BN_h fused)
    stage_split_bn(eb, sEh, sEl, e0, E, t, bnsumsE, bngE, bnbE, invE);
    stage_split_bn_gather(hb, rowS, sHh, sHl, e0, E, t, bnsumsH, bngH, bnbH, invN);

    short8 wfh[4][2], wfl[4][2];
    f32x4 acc[4][2];
    zero_acc(acc);
    load_wfrag_split(Wedge + 256 * H, jb, lane, wfh, wfl);   // W3 (e part)
    __syncthreads();
    mfma_gemm3(sEh, sEl, wfh, wfl, acc, lane);
    load_wfrag_split(Wedge, jb, lane, wfh, wfl);             // W1 (h-row part)
    mfma_gemm3(sHh, sHl, wfh, wfl, acc, lane);
    __syncthreads();   // all reads of sE done -> safe to overwrite with e'

    // epilogue 1: e' = relu(acc + B[col] + be) -> global stream + split back to sE
    float s1[2] = {0.f, 0.f}, s2[2] = {0.f, 0.f};
#pragma unroll
    for (int fr = 0; fr < 4; ++fr)
#pragma unroll
        for (int c = 0; c < 2; ++c) {
            int j = jb + 16 * c + c0;
            float bej = be[j];
#pragma unroll
            for (int r = 0; r < 4; ++r) {
                int Rl = 16 * fr + 4 * g + r;
                int p  = e0 + Rl;
                float v = acc[fr][c][r] + bPre[fr][c][r] + bej;
                v = fmaxf(v, 0.f);
                if (p < E) {
                    eb[(size_t)p * H + j] = v;
                    s1[c] += v;
                    s2[c] += v * v;
                }
                int addr = (Rl << 7) + (j ^ ((Rl & 7) << 3));
                BfPair pp = split2(v);
                sEh[addr] = (unsigned short)pp.hi;
                sEl[addr] = (unsigned short)pp.lo;
            }
        }
    __syncthreads();

    // GEMM2: m = e'@U2 + hrow@U1
    zero_acc(acc);
    load_wfrag_split(Wn1 + 128 * H, jb, lane, wfh, wfl);     // U2 (e' part)
    mfma_gemm3(sEh, sEl, wfh, wfl, acc, lane);
    load_wfrag_split(Wn1, jb, lane, wfh, wfl);               // U1 (h-row part)
    mfma_gemm3(sHh, sHl, wfh, wfl, acc, lane);
    __syncthreads();   // all reads of sE done -> mbuf overlay safe

    // epilogue 2: m -> mbuf (swizzled)
#pragma unroll
    for (int fr = 0; fr < 4; ++fr)
#pragma unroll
        for (int c = 0; c < 2; ++c) {
            int j = jb + 16 * c + c0;
            float b1j = b1[j];
#pragma unroll
            for (int r = 0; r < 4; ++r) {
                int Rl = 16 * fr + 4 * g + r;
                float v = fmaxf(acc[fr][c][r] + b1j, 0.f);
                mbuf[(Rl << 7) + (j ^ (((Rl >> 2) & 3) << 3))] = v;
            }
        }
    __syncthreads();

    // segmented reduction: thread j walks 64 sorted rows, 1 atomic per segment
    if (t < 128) {
        int j = t;
        float run = 0.f;
        int cur = scol[0];
        for (int row = 0; row < 64; ++row) {
            int cc = scol[row];
            float v = mbuf[(row << 7) + (j ^ (((row >> 2) & 3) << 3))];
            if (cc != cur) {
                atomicAdd(&aggsum[(size_t)cur * H + j], run);
                run = 0.f;
                cur = cc;
            }
            if (e0 + row < E) run += v;
        }
        atomicAdd(&aggsum[(size_t)cur * H + j], run);
    }

    // fused e'-stats
#pragma unroll
    for (int c = 0; c < 2; ++c) {
        float a = s1[c], b = s2[c];
        a += __shfl_xor(a, 16); a += __shfl_xor(a, 32);
        b += __shfl_xor(b, 16); b += __shfl_xor(b, 32);
        if (g == 0) {
            int j = jb + 16 * c + c0;
            atomicAdd(&eStats[j], a);
            atomicAdd(&eStats[H + j], b);
        }
    }
}

// ---------------------------------------------------------------------------
// Node update (in place): h = relu(bn(h)@V1 + (aggsum/max(cnt,1))@V2 + b2)
// fused h-stats
__global__ __launch_bounds__(256, 4) void node_kernel(float* hb,
                                                      const float* __restrict__ aggsum,
                                                      const int* __restrict__ cnt,
                                                      const float* __restrict__ V,
                                                      const float* __restrict__ b2, int M,
                                                      const float* __restrict__ bnsums,
                                                      const float* __restrict__ bng,
                                                      const float* __restrict__ bnb,
                                                      float invM,
                                                      float* __restrict__ hStats)
{
    __shared__ __align__(16) unsigned short sAh[64 * 128];
    __shared__ __align__(16) unsigned short sAl[64 * 128];
    const int t = threadIdx.x, lane = t & 63, w = t >> 6, jb = 32 * w;
    const int r0 = blockIdx.x * 64;
    stage_split_bn(hb, sAh, sAl, r0, M, t, bnsums, bng, bnb, invM);
    short8 wfh[4][2], wfl[4][2];
    load_wfrag_split(V, jb, lane, wfh, wfl);
    f32x4 acc[4][2];
    zero_acc(acc);
    __syncthreads();
    mfma_gemm3(sAh, sAl, wfh, wfl, acc, lane);
    __syncthreads();   // h-tile reads done
    stage_agg_split(aggsum, cnt, sAh, sAl, r0, M, t);
    load_wfrag_split(V + H * H, jb, lane, wfh, wfl);
    __syncthreads();
    mfma_gemm3(sAh, sAl, wfh, wfl, acc, lane);
    const int g = lane >> 4, c0 = lane & 15;
    float s1[2] = {0.f, 0.f}, s2[2] = {0.f, 0.f};
#pragma unroll
    for (int fr = 0; fr < 4; ++fr)
#pragma unroll
        for (int c = 0; c < 2; ++c) {
            int j = jb + 16 * c + c0;
            float bj = b2[j];
#pragma unroll
            for (int r = 0; r < 4; ++r) {
                int row = r0 + 16 * fr + 4 * g + r;
                if (row < M) {
                    float v = fmaxf(acc[fr][c][r] + bj, 0.f);
                    hb[(size_t)row * H + j] = v;
                    s1[c] += v;
                    s2[c] += v * v;
                }
            }
        }
#pragma unroll
    for (int c = 0; c < 2; ++c) {
        float a = s1[c], b = s2[c];
        a += __shfl_xor(a, 16); a += __shfl_xor(a, 32);
        b += __shfl_xor(b, 16); b += __shfl_xor(b, 32);
        if (g == 0) {
            int j = jb + 16 * c + c0;
            atomicAdd(&hStats[j], a);
            atomicAdd(&hStats[H + j], b);
        }
    }
}

// ---------------------------------------------------------------------------
// Final readout: out = [mean(h) | mean(e)] @ reg_w + reg_b
__global__ __launch_bounds__(256) void final_kernel(const float* __restrict__ hsum,
                                                    const float* __restrict__ esum,
                                                    const float* __restrict__ reg_w,
                                                    const float* __restrict__ reg_b,
                                                    float* __restrict__ out,
                                                    float invN, float invE)
{
    __shared__ float red[256];
    int t = threadIdx.x;
    float v = (t < 128) ? hsum[t] * invN * reg_w[t]
                        : esum[t - 128] * invE * reg_w[t];
    red[t] = v;
    __syncthreads();
    for (int s = 128; s > 0; s >>= 1) {
        if (t < s) red[t] += red[t + s];
        __syncthreads();
    }
    if (t == 0) out[0] = red[0] + reg_b[0];
}

// ---------------------------------------------------------------------------
extern "C" void kernel_launch(void* const* d_in, const int* in_sizes, int n_in,
                              void* d_out, int out_size, void* d_ws, size_t ws_size,
                              hipStream_t stream)
{
    const float* x          = (const float*)d_in[0];
    const int*   edge_index = (const int*)  d_in[1];
    const float* edge_attr  = (const float*)d_in[2];
    const float* enc_node_w = (const float*)d_in[3];
    const float* enc_node_b = (const float*)d_in[4];
    const float* enc_edge_w = (const float*)d_in[5];
    const float* enc_edge_b = (const float*)d_in[6];
    const float* edge_w     = (const float*)d_in[7];
    const float* edge_b     = (const float*)d_in[8];
    const float* n1_w       = (const float*)d_in[9];
    const float* n1_b       = (const float*)d_in[10];
    const float* n2_w       = (const float*)d_in[11];
    const float* n2_b       = (const float*)d_in[12];
    const float* bn_node_g  = (const float*)d_in[13];
    const float* bn_node_b  = (const float*)d_in[14];
    const float* bn_edge_g  = (const float*)d_in[15];
    const float* bn_edge_b  = (const float*)d_in[16];
    const float* reg_w      = (const float*)d_in[17];
    const float* reg_b      = (const float*)d_in[18];

    const int N = in_sizes[0] / F_IN;
    const int E = in_sizes[1] / 2;
    const size_t NH = (size_t)N * H;
    const size_t EH = (size_t)E * H;

    float* ws     = (float*)d_ws;
    float* hbuf   = ws;                 // [N,128]
    float* ebuf   = hbuf + NH;          // [E,128]  (stored in col-sorted order)
    float* Bbuf   = ebuf + EH;          // [N,128]
    float* aggsum = Bbuf + NH;          // [N,128]
    float* statsA = aggsum + NH;        // 512
    float* statsB = statsA + 512;       // 512
    int*   cnt_i  = (int*)(statsB + 512);   // [N]
    int*   tmpc   = cnt_i + N;              // [N]
    int*   offs   = tmpc + N;               // [N+1]
    int*   sortedIds = offs + N + 1;        // [E]
    int*   rowS   = sortedIds + E;          // [E]
    int*   colS   = rowS + E;               // [E]

    const int* row_idx = edge_index;
    const int* col_idx = edge_index + E;
    const float invN = 1.f / (float)N;
    const float invE = 1.f / (float)E;

    // one-time: sort edges by col, build permuted index arrays
    (void)hipMemsetAsync(cnt_i, 0, (size_t)2 * N * sizeof(int), stream);
    hist_kernel<<<(E + 255) / 256, 256, 0, stream>>>(col_idx, cnt_i, E);
    scan_kernel<<<1, 1024, 0, stream>>>(cnt_i, offs, N);
    scatter_kernel<<<(E + 255) / 256, 256, 0, stream>>>(row_idx, col_idx, offs, tmpc,
                                                        sortedIds, rowS, colS, E);

    enc_kernel<<<(N + 1) / 2, 256, 0, stream>>>(x, enc_node_w, enc_node_b, hbuf, N);
    enc_gather_kernel<<<(E + 1) / 2, 256, 0, stream>>>(edge_attr, sortedIds,
                                                       enc_edge_w, enc_edge_b, ebuf, E);

    const int nodeBlocks = (N + 63) / 64;
    const int edgeBlocks = (E + 63) / 64;

    for (int i = 0; i < 3; ++i) {
        float*       Scur  = (i & 1) ? statsB : statsA;
        const float* Sprev = (i == 0) ? nullptr : ((i & 1) ? statsA : statsB);
        (void)hipMemsetAsync(aggsum, 0, NH * sizeof(float), stream);
        (void)hipMemsetAsync(Scur, 0, 512 * sizeof(float), stream);
        bk_kernel<<<nodeBlocks, 256, 0, stream>>>(
            hbuf, edge_w + (size_t)i * 384 * H + 128 * H,   // W2
            Bbuf, N, Sprev, bn_node_g, bn_node_b, invN);
        edge_kernel<<<edgeBlocks, 256, 0, stream>>>(
            ebuf, rowS, colS, hbuf, Bbuf,
            edge_w + (size_t)i * 384 * H,                   // W1|W2|W3 base
            n1_w + (size_t)i * 256 * H,                     // U1|U2 base
            edge_b + i * H, n1_b + i * H,
            aggsum, E,
            Sprev ? Sprev + 256 : nullptr, bn_edge_g, bn_edge_b, invE,
            Sprev, bn_node_g, bn_node_b, invN,
            Scur + 256);
        node_kernel<<<nodeBlocks, 256, 0, stream>>>(
            hbuf, aggsum, cnt_i, n2_w + (size_t)i * 256 * H, n2_b + i * H, N,
            Sprev, bn_node_g, bn_node_b, invN,
            Scur);
    }
    // i=2 wrote statsA
    final_kernel<<<1, 256, 0, stream>>>(statsA, statsA + 256, reg_w, reg_b,
                                        (float*)d_out, invN, invE);
}

// Round 11
// 1060.074 us; speedup vs baseline: 2.4575x; 1.2094x over previous
//
#include <hip/hip_runtime.h>

#define H 128
#define F_IN 16

typedef __attribute__((ext_vector_type(8))) short short8;
typedef __attribute__((ext_vector_type(4))) float f32x4;

// f32 -> bf16 round-to-nearest-even
__device__ __forceinline__ unsigned short f2bf(float f)
{
    unsigned u = __builtin_bit_cast(unsigned, f);
    u += 0x7FFFu + ((u >> 16) & 1u);
    return (unsigned short)(u >> 16);
}
__device__ __forceinline__ float bf2f(unsigned short h)
{
    return __builtin_bit_cast(float, (unsigned)h << 16);
}
struct BfPair { short hi, lo; };
// Split: x ≈ bf2f(hi) + bf2f(lo), residual ~2^-18 |x|
__device__ __forceinline__ BfPair split2(float x)
{
    BfPair p;
    unsigned short h = f2bf(x);
    p.hi = (short)h;
    p.lo = (short)f2bf(x - bf2f(h));
    return p;
}

// ---------------------------------------------------------------------------
// Stage a 64x128 f32 tile (rows r0..) as split bf16 into swizzled LDS, with
// optional fused BatchNorm. element (row,k) -> ushort idx row*128 + (k ^ ((row&7)<<3))
__device__ __forceinline__ void stage_split_bn(const float* __restrict__ src,
                                               unsigned short* sH, unsigned short* sL,
                                               int r0, int M, int t,
                                               const float* __restrict__ bnsums,
                                               const float* __restrict__ bng,
                                               const float* __restrict__ bnb,
                                               float invM)
{
#pragma unroll
    for (int i = 0; i < 4; ++i) {
        int cid  = t + 256 * i;
        int row  = cid >> 4;
        int ck   = cid & 15;
        int grow = r0 + row;
        short8 ph = (short8)0, pl = (short8)0;
        if (grow < M) {
            const float4* q = (const float4*)(src + (size_t)grow * H + ck * 8);
            float4 a = q[0], b = q[1];
            float xs[8] = {a.x, a.y, a.z, a.w, b.x, b.y, b.z, b.w};
            if (bnsums) {
                int j0 = ck * 8;
#pragma unroll
                for (int j = 0; j < 8; ++j) {
                    float mean = bnsums[j0 + j] * invM;
                    float var  = bnsums[H + j0 + j] * invM - mean * mean;
                    float s    = rsqrtf(var + 1e-5f) * bng[j0 + j];
                    xs[j] = (xs[j] - mean) * s + bnb[j0 + j];
                }
            }
#pragma unroll
            for (int j = 0; j < 8; ++j) {
                BfPair p = split2(xs[j]);
                ph[j] = p.hi;
                pl[j] = p.lo;
            }
        }
        int addr = (row << 7) + ((ck ^ (row & 7)) << 3);
        *(short8*)(sH + addr) = ph;
        *(short8*)(sL + addr) = pl;
    }
}

// Gather variant: tile row i holds src[idx[p0+i]], with fused BN.
__device__ __forceinline__ void stage_split_bn_gather(const float* __restrict__ src,
                                                      const int* __restrict__ idx,
                                                      unsigned short* sH, unsigned short* sL,
                                                      int p0, int M, int t,
                                                      const float* __restrict__ bnsums,
                                                      const float* __restrict__ bng,
                                                      const float* __restrict__ bnb,
                                                      float invM)
{
#pragma unroll
    for (int i = 0; i < 4; ++i) {
        int cid = t + 256 * i;
        int row = cid >> 4;
        int ck  = cid & 15;
        int p   = p0 + row;
        short8 ph = (short8)0, pl = (short8)0;
        if (p < M) {
            int srcRow = idx[p];
            const float4* q = (const float4*)(src + (size_t)srcRow * H + ck * 8);
            float4 a = q[0], b = q[1];
            float xs[8] = {a.x, a.y, a.z, a.w, b.x, b.y, b.z, b.w};
            if (bnsums) {
                int j0 = ck * 8;
#pragma unroll
                for (int j = 0; j < 8; ++j) {
                    float mean = bnsums[j0 + j] * invM;
                    float var  = bnsums[H + j0 + j] * invM - mean * mean;
                    float s    = rsqrtf(var + 1e-5f) * bng[j0 + j];
                    xs[j] = (xs[j] - mean) * s + bnb[j0 + j];
                }
            }
#pragma unroll
            for (int j = 0; j < 8; ++j) {
                BfPair pp = split2(xs[j]);
                ph[j] = pp.hi;
                pl[j] = pp.lo;
            }
        }
        int addr = (row << 7) + ((ck ^ (row & 7)) << 3);
        *(short8*)(sH + addr) = ph;
        *(short8*)(sL + addr) = pl;
    }
}

// value = aggsum[row][k] / max(cnt[row],1) (int counts)
__device__ __forceinline__ void stage_agg_split(const float* __restrict__ aggsum,
                                                const int* __restrict__ cnt,
                                                unsigned short* sH, unsigned short* sL,
                                                int r0, int M, int t)
{
#pragma unroll
    for (int i = 0; i < 4; ++i) {
        int cid  = t + 256 * i;
        int row  = cid >> 4;
        int ck   = cid & 15;
        int grow = r0 + row;
        short8 ph = (short8)0, pl = (short8)0;
        if (grow < M) {
            const float4* q = (const float4*)(aggsum + (size_t)grow * H + ck * 8);
            float4 a = q[0], b = q[1];
            int c = cnt[grow];
            float inv = 1.f / (float)(c > 1 ? c : 1);
            float xs[8] = {a.x * inv, a.y * inv, a.z * inv, a.w * inv,
                           b.x * inv, b.y * inv, b.z * inv, b.w * inv};
#pragma unroll
            for (int j = 0; j < 8; ++j) {
                BfPair p = split2(xs[j]);
                ph[j] = p.hi;
                pl[j] = p.lo;
            }
        }
        int addr = (row << 7) + ((ck ^ (row & 7)) << 3);
        *(short8*)(sH + addr) = ph;
        *(short8*)(sL + addr) = pl;
    }
}

// ---------------------------------------------------------------------------
// One-time weight split+fragment precompute.
// Matrix m (21 total): layer=m/7, k=m%7: k<3 -> edge_w{W1,W2,W3}; k<5 -> n1_w{U1,U2};
// else n2_w{V1,V2}. Output per matrix: 4096 short8 (2048 hi, 2048 lo),
// entry idx = ((jbB*4+s)*2+c)*64+lane holds W[32s+8g+j][jbB*32+16c+c0] fragment.
__global__ __launch_bounds__(256) void wsplit_kernel(const float* __restrict__ edge_w,
                                                     const float* __restrict__ n1_w,
                                                     const float* __restrict__ n2_w,
                                                     short8* __restrict__ out)
{
    int m = blockIdx.x;
    int layer = m / 7, k = m % 7;
    const float* W = (k < 3) ? edge_w + (size_t)layer * 384 * H + (size_t)k * H * H
                   : (k < 5) ? n1_w + (size_t)layer * 256 * H + (size_t)(k - 3) * H * H
                             : n2_w + (size_t)layer * 256 * H + (size_t)(k - 5) * H * H;
    short8* oh = out + (size_t)m * 4096;
    for (int e = threadIdx.x; e < 2048; e += 256) {
        int jbB = e >> 9, s = (e >> 7) & 3, c = (e >> 6) & 1, lane = e & 63;
        int g = lane >> 4, c0 = lane & 15;
        short8 hi, lo;
#pragma unroll
        for (int j = 0; j < 8; ++j) {
            int kk = 32 * s + 8 * g + j;
            BfPair p = split2(W[(size_t)kk * H + jbB * 32 + 16 * c + c0]);
            hi[j] = p.hi;
            lo[j] = p.lo;
        }
        oh[e] = hi;
        oh[e + 2048] = lo;
    }
}

// Load precomputed split fragments: 16 coalesced 16B loads, zero VALU.
__device__ __forceinline__ void load_wfrag_pre(const short8* __restrict__ Wp, int jbB,
                                               int lane, short8 wfh[4][2], short8 wfl[4][2])
{
#pragma unroll
    for (int s = 0; s < 4; ++s)
#pragma unroll
        for (int c = 0; c < 2; ++c) {
            int idx = ((jbB * 4 + s) * 2 + c) * 64 + lane;
            wfh[s][c] = Wp[idx];
            wfl[s][c] = Wp[idx + 2048];
        }
}

// acc += (sH+sL) @ (Wh+Wl), 3 MFMA products per k-step (al@wl dropped)
__device__ __forceinline__ void mfma_gemm3(const unsigned short* sH, const unsigned short* sL,
                                           const short8 wfh[4][2], const short8 wfl[4][2],
                                           f32x4 acc[4][2], int lane)
{
    const int g = lane >> 4, r = lane & 15;
#pragma unroll
    for (int s = 0; s < 4; ++s) {
        short8 ah[4], al[4];
#pragma unroll
        for (int fr = 0; fr < 4; ++fr) {
            int row  = 16 * fr + r;
            int ck   = (4 * s + g) ^ (row & 7);
            int addr = (row << 7) + (ck << 3);
            ah[fr] = *(const short8*)(sH + addr);
            al[fr] = *(const short8*)(sL + addr);
        }
#pragma unroll
        for (int fr = 0; fr < 4; ++fr)
#pragma unroll
            for (int c = 0; c < 2; ++c) {
                f32x4 a = acc[fr][c];
                a = __builtin_amdgcn_mfma_f32_16x16x32_bf16(ah[fr], wfh[s][c], a, 0, 0, 0);
                a = __builtin_amdgcn_mfma_f32_16x16x32_bf16(al[fr], wfh[s][c], a, 0, 0, 0);
                a = __builtin_amdgcn_mfma_f32_16x16x32_bf16(ah[fr], wfl[s][c], a, 0, 0, 0);
                acc[fr][c] = a;
            }
    }
}

__device__ __forceinline__ void zero_acc(f32x4 acc[4][2])
{
#pragma unroll
    for (int fr = 0; fr < 4; ++fr)
#pragma unroll
        for (int c = 0; c < 2; ++c) {
            acc[fr][c][0] = 0.f; acc[fr][c][1] = 0.f;
            acc[fr][c][2] = 0.f; acc[fr][c][3] = 0.f;
        }
}

// ---------------------------------------------------------------------------
// One-time sort machinery (edge_index is layer-invariant)
__global__ __launch_bounds__(256) void hist_kernel(const int* __restrict__ col,
                                                   int* __restrict__ cnt, int E)
{
    int e = blockIdx.x * 256 + threadIdx.x;
    if (e < E) atomicAdd(&cnt[col[e]], 1);
}

__global__ __launch_bounds__(1024) void scan_kernel(const int* __restrict__ cnt,
                                                    int* __restrict__ offs, int Nn)
{
    __shared__ int ls[1024];
    int t = threadIdx.x;
    int per = (Nn + 1023) / 1024;
    int base = t * per;
    int s = 0;
    for (int k = 0; k < per; ++k) {
        int i = base + k;
        if (i < Nn) s += cnt[i];
    }
    ls[t] = s;
    __syncthreads();
    for (int d = 1; d < 1024; d <<= 1) {
        int u = (t >= d) ? ls[t - d] : 0;
        __syncthreads();
        ls[t] += u;
        __syncthreads();
    }
    int run = ls[t] - s;
    for (int k = 0; k < per; ++k) {
        int i = base + k;
        if (i < Nn) {
            offs[i] = run;
            run += cnt[i];
        }
    }
}

__global__ __launch_bounds__(256) void scatter_kernel(const int* __restrict__ row,
                                                      const int* __restrict__ col,
                                                      const int* __restrict__ offs,
                                                      int* __restrict__ tmpc,
                                                      int* __restrict__ sortedIds,
                                                      int* __restrict__ rowS,
                                                      int* __restrict__ colS, int E)
{
    int e = blockIdx.x * 256 + threadIdx.x;
    if (e < E) {
        int c = col[e];
        int p = offs[c] + atomicAdd(&tmpc[c], 1);
        sortedIds[p] = e;
        rowS[p] = row[e];
        colS[p] = c;
    }
}

// ---------------------------------------------------------------------------
// Encoder: out = relu(X[M,16] @ W[16,128] + b)
__global__ __launch_bounds__(256) void enc_kernel(const float* __restrict__ X,
                                                  const float* __restrict__ W,
                                                  const float* __restrict__ bias,
                                                  float* __restrict__ out, int M)
{
    __shared__ float sW[F_IN * H];
    __shared__ float sb[H];
    int t = threadIdx.x;
    reinterpret_cast<float4*>(sW)[t]       = reinterpret_cast<const float4*>(W)[t];
    reinterpret_cast<float4*>(sW)[t + 256] = reinterpret_cast<const float4*>(W)[t + 256];
    if (t < H) sb[t] = bias[t];
    __syncthreads();
    int row = blockIdx.x * 2 + (t >> 7);
    if (row >= M) return;
    int j = t & 127;
    float acc = sb[j];
#pragma unroll
    for (int k = 0; k < F_IN; ++k)
        acc += X[(size_t)row * F_IN + k] * sW[k * H + j];
    out[(size_t)row * H + j] = fmaxf(acc, 0.f);
}

// Gather-encoder: out[p] = relu(X[sortedIds[p],16] @ W + b)  (one-time)
__global__ __launch_bounds__(256) void enc_gather_kernel(const float* __restrict__ X,
                                                         const int* __restrict__ sortedIds,
                                                         const float* __restrict__ W,
                                                         const float* __restrict__ bias,
                                                         float* __restrict__ out, int M)
{
    __shared__ float sW[F_IN * H];
    __shared__ float sb[H];
    int t = threadIdx.x;
    reinterpret_cast<float4*>(sW)[t]       = reinterpret_cast<const float4*>(W)[t];
    reinterpret_cast<float4*>(sW)[t + 256] = reinterpret_cast<const float4*>(W)[t + 256];
    if (t < H) sb[t] = bias[t];
    __syncthreads();
    int p = blockIdx.x * 2 + (t >> 7);
    if (p >= M) return;
    int src = sortedIds[p];
    int j = t & 127;
    float acc = sb[j];
#pragma unroll
    for (int k = 0; k < F_IN; ++k)
        acc += X[(size_t)src * F_IN + k] * sW[k * H + j];
    out[(size_t)p * H + j] = fmaxf(acc, 0.f);
}

// ---------------------------------------------------------------------------
// B-only precompute: B = bn(h)@W2 (raw output).
__global__ __launch_bounds__(256, 4) void bk_kernel(const float* __restrict__ hb,
                                                    const short8* __restrict__ W2p,
                                                    float* __restrict__ Bout, int M,
                                                    const float* __restrict__ bnsums,
                                                    const float* __restrict__ bng,
                                                    const float* __restrict__ bnb,
                                                    float invM)
{
    __shared__ __align__(16) unsigned short sAh[64 * 128];
    __shared__ __align__(16) unsigned short sAl[64 * 128];
    const int t = threadIdx.x, lane = t & 63, w = t >> 6, jb = 32 * w;
    const int r0 = blockIdx.x * 64;
    stage_split_bn(hb, sAh, sAl, r0, M, t, bnsums, bng, bnb, invM);
    const int g = lane >> 4, c0 = lane & 15;
    short8 wfh[4][2], wfl[4][2];
    load_wfrag_pre(W2p, w, lane, wfh, wfl);
    f32x4 acc[4][2];
    zero_acc(acc);
    __syncthreads();
    mfma_gemm3(sAh, sAl, wfh, wfl, acc, lane);
#pragma unroll
    for (int fr = 0; fr < 4; ++fr)
#pragma unroll
        for (int c = 0; c < 2; ++c) {
            int j = jb + 16 * c + c0;
#pragma unroll
            for (int r = 0; r < 4; ++r) {
                int row = r0 + 16 * fr + 4 * g + r;
                if (row < M) Bout[(size_t)row * H + j] = acc[fr][c][r];
            }
        }
}

// ---------------------------------------------------------------------------
// Fused edge kernel over col-sorted e layout:
//   e'[p] = relu(bn(e[p])@W3 + bn(h)[rowS]@W1 + B[colS] + be)
//   m     = relu(e'@U2 + bn(h)[rowS]@U1 + b1)
//   aggsum[col] += segment-reduced m ; fused e'-stats
__global__ __launch_bounds__(256, 2) void edge_kernel(float* eb,
                                                      const int* __restrict__ rowS,
                                                      const int* __restrict__ colS,
                                                      const float* __restrict__ hb,
                                                      const float* __restrict__ Bsrc,
                                                      const short8* __restrict__ W1p,
                                                      const short8* __restrict__ W3p,
                                                      const short8* __restrict__ U1p,
                                                      const short8* __restrict__ U2p,
                                                      const float* __restrict__ be,
                                                      const float* __restrict__ b1,
                                                      float* __restrict__ aggsum, int E,
                                                      const float* __restrict__ bnsumsE,
                                                      const float* __restrict__ bngE,
                                                      const float* __restrict__ bnbE,
                                                      float invE,
                                                      const float* __restrict__ bnsumsH,
                                                      const float* __restrict__ bngH,
                                                      const float* __restrict__ bnbH,
                                                      float invN,
                                                      float* __restrict__ eStats)
{
    __shared__ __align__(16) unsigned char smem[64 * 128 * 8 + 256];
    unsigned short* sEh = (unsigned short*)smem;          // 16 KB  e  (hi)
    unsigned short* sEl = sEh + 64 * 128;                 // 16 KB  e  (lo)
    unsigned short* sHh = sEl + 64 * 128;                 // 16 KB  h[row] (hi)
    unsigned short* sHl = sHh + 64 * 128;                 // 16 KB  h[row] (lo)
    float*          mbuf = (float*)smem;                  // 32 KB overlay on sE pair
    int*            scol = (int*)(smem + 64 * 128 * 8);   // 256 B

    const int t = threadIdx.x, lane = t & 63, w = t >> 6, jb = 32 * w;
    const int e0 = blockIdx.x * 64;
    const int g = lane >> 4, c0 = lane & 15;

    if (t < 64) scol[t] = colS[(e0 + t < E) ? (e0 + t) : (E - 1)];

    // per-lane col indices + early B prefetch
    int cidx[4][4];
#pragma unroll
    for (int fr = 0; fr < 4; ++fr)
#pragma unroll
        for (int r = 0; r < 4; ++r) {
            int p  = e0 + 16 * fr + 4 * g + r;
            int pc = (p < E) ? p : (E - 1);
            cidx[fr][r] = colS[pc];
        }
    float bPre[4][2][4];
#pragma unroll
    for (int fr = 0; fr < 4; ++fr)
#pragma unroll
        for (int c = 0; c < 2; ++c)
#pragma unroll
            for (int r = 0; r < 4; ++r)
                bPre[fr][c][r] = Bsrc[(size_t)cidx[fr][r] * H + jb + 16 * c + c0];

    // stage e tile (BN_e fused) + gathered h[row] tile (BN_h fused)
    stage_split_bn(eb, sEh, sEl, e0, E, t, bnsumsE, bngE, bnbE, invE);
    stage_split_bn_gather(hb, rowS, sHh, sHl, e0, E, t, bnsumsH, bngH, bnbH, invN);

    short8 wfh[4][2], wfl[4][2];
    f32x4 acc[4][2];
    zero_acc(acc);
    load_wfrag_pre(W3p, w, lane, wfh, wfl);
    __syncthreads();
    mfma_gemm3(sEh, sEl, wfh, wfl, acc, lane);
    load_wfrag_pre(W1p, w, lane, wfh, wfl);
    mfma_gemm3(sHh, sHl, wfh, wfl, acc, lane);
    __syncthreads();   // all reads of sE done -> safe to overwrite with e'

    // epilogue 1: e' = relu(acc + B[col] + be) -> global stream + split back to sE
    float s1[2] = {0.f, 0.f}, s2[2] = {0.f, 0.f};
#pragma unroll
    for (int fr = 0; fr < 4; ++fr)
#pragma unroll
        for (int c = 0; c < 2; ++c) {
            int j = jb + 16 * c + c0;
            float bej = be[j];
#pragma unroll
            for (int r = 0; r < 4; ++r) {
                int Rl = 16 * fr + 4 * g + r;
                int p  = e0 + Rl;
                float v = acc[fr][c][r] + bPre[fr][c][r] + bej;
                v = fmaxf(v, 0.f);
                if (p < E) {
                    eb[(size_t)p * H + j] = v;
                    s1[c] += v;
                    s2[c] += v * v;
                }
                int addr = (Rl << 7) + (j ^ ((Rl & 7) << 3));
                BfPair pp = split2(v);
                sEh[addr] = (unsigned short)pp.hi;
                sEl[addr] = (unsigned short)pp.lo;
            }
        }
    __syncthreads();

    // GEMM2: m = e'@U2 + hrow@U1
    zero_acc(acc);
    load_wfrag_pre(U2p, w, lane, wfh, wfl);
    mfma_gemm3(sEh, sEl, wfh, wfl, acc, lane);
    load_wfrag_pre(U1p, w, lane, wfh, wfl);
    mfma_gemm3(sHh, sHl, wfh, wfl, acc, lane);
    __syncthreads();   // all reads of sE done -> mbuf overlay safe

    // epilogue 2: m -> mbuf (swizzled)
#pragma unroll
    for (int fr = 0; fr < 4; ++fr)
#pragma unroll
        for (int c = 0; c < 2; ++c) {
            int j = jb + 16 * c + c0;
            float b1j = b1[j];
#pragma unroll
            for (int r = 0; r < 4; ++r) {
                int Rl = 16 * fr + 4 * g + r;
                float v = fmaxf(acc[fr][c][r] + b1j, 0.f);
                mbuf[(Rl << 7) + (j ^ (((Rl >> 2) & 3) << 3))] = v;
            }
        }
    __syncthreads();

    // segmented reduction: thread j walks 64 sorted rows, 1 atomic per segment
    if (t < 128) {
        int j = t;
        float run = 0.f;
        int cur = scol[0];
        for (int row = 0; row < 64; ++row) {
            int cc = scol[row];
            float v = mbuf[(row << 7) + (j ^ (((row >> 2) & 3) << 3))];
            if (cc != cur) {
                atomicAdd(&aggsum[(size_t)cur * H + j], run);
                run = 0.f;
                cur = cc;
            }
            if (e0 + row < E) run += v;
        }
        atomicAdd(&aggsum[(size_t)cur * H + j], run);
    }

    // fused e'-stats
#pragma unroll
    for (int c = 0; c < 2; ++c) {
        float a = s1[c], b = s2[c];
        a += __shfl_xor(a, 16); a += __shfl_xor(a, 32);
        b += __shfl_xor(b, 16); b += __shfl_xor(b, 32);
        if (g == 0) {
            int j = jb + 16 * c + c0;
            atomicAdd(&eStats[j], a);
            atomicAdd(&eStats[H + j], b);
        }
    }
}

// ---------------------------------------------------------------------------
// Node update (in place): h = relu(bn(h)@V1 + (aggsum/max(cnt,1))@V2 + b2)
// fused h-stats
__global__ __launch_bounds__(256, 4) void node_kernel(float* hb,
                                                      const float* __restrict__ aggsum,
                                                      const int* __restrict__ cnt,
                                                      const short8* __restrict__ V1p,
                                                      const short8* __restrict__ V2p,
                                                      const float* __restrict__ b2, int M,
                                                      const float* __restrict__ bnsums,
                                                      const float* __restrict__ bng,
                                                      const float* __restrict__ bnb,
                                                      float invM,
                                                      float* __restrict__ hStats)
{
    __shared__ __align__(16) unsigned short sAh[64 * 128];
    __shared__ __align__(16) unsigned short sAl[64 * 128];
    const int t = threadIdx.x, lane = t & 63, w = t >> 6, jb = 32 * w;
    const int r0 = blockIdx.x * 64;
    stage_split_bn(hb, sAh, sAl, r0, M, t, bnsums, bng, bnb, invM);
    short8 wfh[4][2], wfl[4][2];
    load_wfrag_pre(V1p, w, lane, wfh, wfl);
    f32x4 acc[4][2];
    zero_acc(acc);
    __syncthreads();
    mfma_gemm3(sAh, sAl, wfh, wfl, acc, lane);
    __syncthreads();   // h-tile reads done
    stage_agg_split(aggsum, cnt, sAh, sAl, r0, M, t);
    load_wfrag_pre(V2p, w, lane, wfh, wfl);
    __syncthreads();
    mfma_gemm3(sAh, sAl, wfh, wfl, acc, lane);
    const int g = lane >> 4, c0 = lane & 15;
    float s1[2] = {0.f, 0.f}, s2[2] = {0.f, 0.f};
#pragma unroll
    for (int fr = 0; fr < 4; ++fr)
#pragma unroll
        for (int c = 0; c < 2; ++c) {
            int j = jb + 16 * c + c0;
            float bj = b2[j];
#pragma unroll
            for (int r = 0; r < 4; ++r) {
                int row = r0 + 16 * fr + 4 * g + r;
                if (row < M) {
                    float v = fmaxf(acc[fr][c][r] + bj, 0.f);
                    hb[(size_t)row * H + j] = v;
                    s1[c] += v;
                    s2[c] += v * v;
                }
            }
        }
#pragma unroll
    for (int c = 0; c < 2; ++c) {
        float a = s1[c], b = s2[c];
        a += __shfl_xor(a, 16); a += __shfl_xor(a, 32);
        b += __shfl_xor(b, 16); b += __shfl_xor(b, 32);
        if (g == 0) {
            int j = jb + 16 * c + c0;
            atomicAdd(&hStats[j], a);
            atomicAdd(&hStats[H + j], b);
        }
    }
}

// ---------------------------------------------------------------------------
// Final readout: out = [mean(h) | mean(e)] @ reg_w + reg_b
__global__ __launch_bounds__(256) void final_kernel(const float* __restrict__ hsum,
                                                    const float* __restrict__ esum,
                                                    const float* __restrict__ reg_w,
                                                    const float* __restrict__ reg_b,
                                                    float* __restrict__ out,
                                                    float invN, float invE)
{
    __shared__ float red[256];
    int t = threadIdx.x;
    float v = (t < 128) ? hsum[t] * invN * reg_w[t]
                        : esum[t - 128] * invE * reg_w[t];
    red[t] = v;
    __syncthreads();
    for (int s = 128; s > 0; s >>= 1) {
        if (t < s) red[t] += red[t + s];
        __syncthreads();
    }
    if (t == 0) out[0] = red[0] + reg_b[0];
}

// ---------------------------------------------------------------------------
extern "C" void kernel_launch(void* const* d_in, const int* in_sizes, int n_in,
                              void* d_out, int out_size, void* d_ws, size_t ws_size,
                              hipStream_t stream)
{
    const float* x          = (const float*)d_in[0];
    const int*   edge_index = (const int*)  d_in[1];
    const float* edge_attr  = (const float*)d_in[2];
    const float* enc_node_w = (const float*)d_in[3];
    const float* enc_node_b = (const float*)d_in[4];
    const float* enc_edge_w = (const float*)d_in[5];
    const float* enc_edge_b = (const float*)d_in[6];
    const float* edge_w     = (const float*)d_in[7];
    const float* edge_b     = (const float*)d_in[8];
    const float* n1_w       = (const float*)d_in[9];
    const float* n1_b       = (const float*)d_in[10];
    const float* n2_w       = (const float*)d_in[11];
    const float* n2_b       = (const float*)d_in[12];
    const float* bn_node_g  = (const float*)d_in[13];
    const float* bn_node_b  = (const float*)d_in[14];
    const float* bn_edge_g  = (const float*)d_in[15];
    const float* bn_edge_b  = (const float*)d_in[16];
    const float* reg_w      = (const float*)d_in[17];
    const float* reg_b      = (const float*)d_in[18];

    const int N = in_sizes[0] / F_IN;
    const int E = in_sizes[1] / 2;
    const size_t NH = (size_t)N * H;
    const size_t EH = (size_t)E * H;

    float* ws     = (float*)d_ws;
    float* hbuf   = ws;                 // [N,128]
    float* ebuf   = hbuf + NH;          // [E,128]  (stored in col-sorted order)
    float* Bbuf   = ebuf + EH;          // [N,128]
    float* aggsum = Bbuf + NH;          // [N,128]
    float* statsA = aggsum + NH;        // 512
    float* statsB = statsA + 512;       // 512
    short8* wsplit = (short8*)(statsB + 512);       // 21 * 4096 short8 = 1.31 MB
    float* afterW = (float*)(wsplit + 21 * 4096);
    int*   cnt_i  = (int*)afterW;           // [N]
    int*   tmpc   = cnt_i + N;              // [N]
    int*   offs   = tmpc + N;               // [N+1]
    int*   sortedIds = offs + N + 1;        // [E]
    int*   rowS   = sortedIds + E;          // [E]
    int*   colS   = rowS + E;               // [E]

    const int* row_idx = edge_index;
    const int* col_idx = edge_index + E;
    const float invN = 1.f / (float)N;
    const float invE = 1.f / (float)E;

    // one-time: sort edges by col, build permuted index arrays; split weights
    (void)hipMemsetAsync(cnt_i, 0, (size_t)2 * N * sizeof(int), stream);
    hist_kernel<<<(E + 255) / 256, 256, 0, stream>>>(col_idx, cnt_i, E);
    scan_kernel<<<1, 1024, 0, stream>>>(cnt_i, offs, N);
    scatter_kernel<<<(E + 255) / 256, 256, 0, stream>>>(row_idx, col_idx, offs, tmpc,
                                                        sortedIds, rowS, colS, E);
    wsplit_kernel<<<21, 256, 0, stream>>>(edge_w, n1_w, n2_w, wsplit);

    enc_kernel<<<(N + 1) / 2, 256, 0, stream>>>(x, enc_node_w, enc_node_b, hbuf, N);
    enc_gather_kernel<<<(E + 1) / 2, 256, 0, stream>>>(edge_attr, sortedIds,
                                                       enc_edge_w, enc_edge_b, ebuf, E);

    const int nodeBlocks = (N + 63) / 64;
    const int edgeBlocks = (E + 63) / 64;

    for (int i = 0; i < 3; ++i) {
        float*       Scur  = (i & 1) ? statsB : statsA;
        const float* Sprev = (i == 0) ? nullptr : ((i & 1) ? statsA : statsB);
        const short8* W1p = wsplit + (size_t)(i * 7 + 0) * 4096;
        const short8* W2p = wsplit + (size_t)(i * 7 + 1) * 4096;
        const short8* W3p = wsplit + (size_t)(i * 7 + 2) * 4096;
        const short8* U1p = wsplit + (size_t)(i * 7 + 3) * 4096;
        const short8* U2p = wsplit + (size_t)(i * 7 + 4) * 4096;
        const short8* V1p = wsplit + (size_t)(i * 7 + 5) * 4096;
        const short8* V2p = wsplit + (size_t)(i * 7 + 6) * 4096;
        (void)hipMemsetAsync(aggsum, 0, NH * sizeof(float), stream);
        (void)hipMemsetAsync(Scur, 0, 512 * sizeof(float), stream);
        bk_kernel<<<nodeBlocks, 256, 0, stream>>>(
            hbuf, W2p, Bbuf, N, Sprev, bn_node_g, bn_node_b, invN);
        edge_kernel<<<edgeBlocks, 256, 0, stream>>>(
            ebuf, rowS, colS, hbuf, Bbuf,
            W1p, W3p, U1p, U2p,
            edge_b + i * H, n1_b + i * H,
            aggsum, E,
            Sprev ? Sprev + 256 : nullptr, bn_edge_g, bn_edge_b, invE,
            Sprev, bn_node_g, bn_node_b, invN,
            Scur + 256);
        node_kernel<<<nodeBlocks, 256, 0, stream>>>(
            hbuf, aggsum, cnt_i, V1p, V2p, n2_b + i * H, N,
            Sprev, bn_node_g, bn_node_b, invN,
            Scur);
    }
    // i=2 wrote statsA
    final_kernel<<<1, 256, 0, stream>>>(statsA, statsA + 256, reg_w, reg_b,
                                        (float*)d_out, invN, invE);
}

// Round 12
// 843.439 us; speedup vs baseline: 3.0886x; 1.2568x over previous
//
#include <hip/hip_runtime.h>

#define H 128
#define F_IN 16

typedef __attribute__((ext_vector_type(8))) short short8;
typedef __attribute__((ext_vector_type(4))) float f32x4;

// f32 -> bf16 round-to-nearest-even
__device__ __forceinline__ unsigned short f2bf(float f)
{
    unsigned u = __builtin_bit_cast(unsigned, f);
    u += 0x7FFFu + ((u >> 16) & 1u);
    return (unsigned short)(u >> 16);
}

// ---------------------------------------------------------------------------
// Stage a 64x128 f32 tile (rows r0..) as bf16 into swizzled LDS, with optional
// fused BatchNorm. element (row,k) -> ushort idx row*128 + (k ^ ((row&7)<<3))
__device__ __forceinline__ void stage_bn_bf16(const float* __restrict__ src,
                                              unsigned short* sA,
                                              int r0, int M, int t,
                                              const float* __restrict__ bnsums,
                                              const float* __restrict__ bng,
                                              const float* __restrict__ bnb,
                                              float invM)
{
#pragma unroll
    for (int i = 0; i < 4; ++i) {
        int cid  = t + 256 * i;
        int row  = cid >> 4;
        int ck   = cid & 15;
        int grow = r0 + row;
        short8 ph = (short8)0;
        if (grow < M) {
            const float4* q = (const float4*)(src + (size_t)grow * H + ck * 8);
            float4 a = q[0], b = q[1];
            float xs[8] = {a.x, a.y, a.z, a.w, b.x, b.y, b.z, b.w};
            if (bnsums) {
                int j0 = ck * 8;
#pragma unroll
                for (int j = 0; j < 8; ++j) {
                    float mean = bnsums[j0 + j] * invM;
                    float var  = bnsums[H + j0 + j] * invM - mean * mean;
                    float s    = rsqrtf(var + 1e-5f) * bng[j0 + j];
                    xs[j] = (xs[j] - mean) * s + bnb[j0 + j];
                }
            }
#pragma unroll
            for (int j = 0; j < 8; ++j) ph[j] = (short)f2bf(xs[j]);
        }
        *(short8*)(sA + (row << 7) + ((ck ^ (row & 7)) << 3)) = ph;
    }
}

// Gather variant: tile row i holds src[idx[p0+i]], with fused BN.
__device__ __forceinline__ void stage_bn_bf16_gather(const float* __restrict__ src,
                                                     const int* __restrict__ idx,
                                                     unsigned short* sA,
                                                     int p0, int M, int t,
                                                     const float* __restrict__ bnsums,
                                                     const float* __restrict__ bng,
                                                     const float* __restrict__ bnb,
                                                     float invM)
{
#pragma unroll
    for (int i = 0; i < 4; ++i) {
        int cid = t + 256 * i;
        int row = cid >> 4;
        int ck  = cid & 15;
        int p   = p0 + row;
        short8 ph = (short8)0;
        if (p < M) {
            int srcRow = idx[p];
            const float4* q = (const float4*)(src + (size_t)srcRow * H + ck * 8);
            float4 a = q[0], b = q[1];
            float xs[8] = {a.x, a.y, a.z, a.w, b.x, b.y, b.z, b.w};
            if (bnsums) {
                int j0 = ck * 8;
#pragma unroll
                for (int j = 0; j < 8; ++j) {
                    float mean = bnsums[j0 + j] * invM;
                    float var  = bnsums[H + j0 + j] * invM - mean * mean;
                    float s    = rsqrtf(var + 1e-5f) * bng[j0 + j];
                    xs[j] = (xs[j] - mean) * s + bnb[j0 + j];
                }
            }
#pragma unroll
            for (int j = 0; j < 8; ++j) ph[j] = (short)f2bf(xs[j]);
        }
        *(short8*)(sA + (row << 7) + ((ck ^ (row & 7)) << 3)) = ph;
    }
}

// value = aggsum[row][k] / max(cnt[row],1) (int counts)
__device__ __forceinline__ void stage_agg_bf16(const float* __restrict__ aggsum,
                                               const int* __restrict__ cnt,
                                               unsigned short* sA, int r0, int M, int t)
{
#pragma unroll
    for (int i = 0; i < 4; ++i) {
        int cid  = t + 256 * i;
        int row  = cid >> 4;
        int ck   = cid & 15;
        int grow = r0 + row;
        short8 ph = (short8)0;
        if (grow < M) {
            const float4* q = (const float4*)(aggsum + (size_t)grow * H + ck * 8);
            float4 a = q[0], b = q[1];
            int c = cnt[grow];
            float inv = 1.f / (float)(c > 1 ? c : 1);
            float xs[8] = {a.x * inv, a.y * inv, a.z * inv, a.w * inv,
                           b.x * inv, b.y * inv, b.z * inv, b.w * inv};
#pragma unroll
            for (int j = 0; j < 8; ++j) ph[j] = (short)f2bf(xs[j]);
        }
        *(short8*)(sA + (row << 7) + ((ck ^ (row & 7)) << 3)) = ph;
    }
}

// ---------------------------------------------------------------------------
// One-time weight bf16 fragment precompute.
// Matrix m (21): layer=m/7, k=m%7: k<3 -> edge_w{W1,W2,W3}; k<5 -> n1_w{U1,U2};
// else n2_w{V1,V2}. Per matrix: 2048 short8; entry idx=((jbB*4+s)*2+c)*64+lane
// holds W[32s+8g+j][jbB*32+16c+c0].
__global__ __launch_bounds__(256) void wbf16_kernel(const float* __restrict__ edge_w,
                                                    const float* __restrict__ n1_w,
                                                    const float* __restrict__ n2_w,
                                                    short8* __restrict__ out)
{
    int m = blockIdx.x;
    int layer = m / 7, k = m % 7;
    const float* W = (k < 3) ? edge_w + (size_t)layer * 384 * H + (size_t)k * H * H
                   : (k < 5) ? n1_w + (size_t)layer * 256 * H + (size_t)(k - 3) * H * H
                             : n2_w + (size_t)layer * 256 * H + (size_t)(k - 5) * H * H;
    short8* oh = out + (size_t)m * 2048;
    for (int e = threadIdx.x; e < 2048; e += 256) {
        int jbB = e >> 9, s = (e >> 7) & 3, c = (e >> 6) & 1, lane = e & 63;
        int g = lane >> 4, c0 = lane & 15;
        short8 hi;
#pragma unroll
        for (int j = 0; j < 8; ++j)
            hi[j] = (short)f2bf(W[(size_t)(32 * s + 8 * g + j) * H + jbB * 32 + 16 * c + c0]);
        oh[e] = hi;
    }
}

// Load precomputed bf16 fragments: 8 coalesced 16B loads.
__device__ __forceinline__ void load_wfrag(const short8* __restrict__ Wp, int jbB,
                                           int lane, short8 wf[4][2])
{
#pragma unroll
    for (int s = 0; s < 4; ++s)
#pragma unroll
        for (int c = 0; c < 2; ++c)
            wf[s][c] = Wp[((jbB * 4 + s) * 2 + c) * 64 + lane];
}

// acc += sA(64x128 bf16, swizzled) @ Wf(128x32 bf16)
__device__ __forceinline__ void mfma_gemm(const unsigned short* sA, const short8 wf[4][2],
                                          f32x4 acc[4][2], int lane)
{
    const int g = lane >> 4, r = lane & 15;
#pragma unroll
    for (int s = 0; s < 4; ++s) {
        short8 a4[4];
#pragma unroll
        for (int fr = 0; fr < 4; ++fr) {
            int row = 16 * fr + r;
            int ck  = (4 * s + g) ^ (row & 7);
            a4[fr] = *(const short8*)(sA + (row << 7) + (ck << 3));
        }
#pragma unroll
        for (int fr = 0; fr < 4; ++fr)
#pragma unroll
            for (int c = 0; c < 2; ++c)
                acc[fr][c] = __builtin_amdgcn_mfma_f32_16x16x32_bf16(a4[fr], wf[s][c],
                                                                     acc[fr][c], 0, 0, 0);
    }
}

__device__ __forceinline__ void zero_acc(f32x4 acc[4][2])
{
#pragma unroll
    for (int fr = 0; fr < 4; ++fr)
#pragma unroll
        for (int c = 0; c < 2; ++c) {
            acc[fr][c][0] = 0.f; acc[fr][c][1] = 0.f;
            acc[fr][c][2] = 0.f; acc[fr][c][3] = 0.f;
        }
}

// ---------------------------------------------------------------------------
// One-time sort machinery (edge_index is layer-invariant)
__global__ __launch_bounds__(256) void hist_kernel(const int* __restrict__ col,
                                                   int* __restrict__ cnt, int E)
{
    int e = blockIdx.x * 256 + threadIdx.x;
    if (e < E) atomicAdd(&cnt[col[e]], 1);
}

__global__ __launch_bounds__(1024) void scan_kernel(const int* __restrict__ cnt,
                                                    int* __restrict__ offs, int Nn)
{
    __shared__ int ls[1024];
    int t = threadIdx.x;
    int per = (Nn + 1023) / 1024;
    int base = t * per;
    int s = 0;
    for (int k = 0; k < per; ++k) {
        int i = base + k;
        if (i < Nn) s += cnt[i];
    }
    ls[t] = s;
    __syncthreads();
    for (int d = 1; d < 1024; d <<= 1) {
        int u = (t >= d) ? ls[t - d] : 0;
        __syncthreads();
        ls[t] += u;
        __syncthreads();
    }
    int run = ls[t] - s;
    for (int k = 0; k < per; ++k) {
        int i = base + k;
        if (i < Nn) {
            offs[i] = run;
            run += cnt[i];
        }
    }
}

__global__ __launch_bounds__(256) void scatter_kernel(const int* __restrict__ row,
                                                      const int* __restrict__ col,
                                                      const int* __restrict__ offs,
                                                      int* __restrict__ tmpc,
                                                      int* __restrict__ sortedIds,
                                                      int* __restrict__ rowS,
                                                      int* __restrict__ colS, int E)
{
    int e = blockIdx.x * 256 + threadIdx.x;
    if (e < E) {
        int c = col[e];
        int p = offs[c] + atomicAdd(&tmpc[c], 1);
        sortedIds[p] = e;
        rowS[p] = row[e];
        colS[p] = c;
    }
}

// ---------------------------------------------------------------------------
// Encoder: out = relu(X[M,16] @ W[16,128] + b)
__global__ __launch_bounds__(256) void enc_kernel(const float* __restrict__ X,
                                                  const float* __restrict__ W,
                                                  const float* __restrict__ bias,
                                                  float* __restrict__ out, int M)
{
    __shared__ float sW[F_IN * H];
    __shared__ float sb[H];
    int t = threadIdx.x;
    reinterpret_cast<float4*>(sW)[t]       = reinterpret_cast<const float4*>(W)[t];
    reinterpret_cast<float4*>(sW)[t + 256] = reinterpret_cast<const float4*>(W)[t + 256];
    if (t < H) sb[t] = bias[t];
    __syncthreads();
    int row = blockIdx.x * 2 + (t >> 7);
    if (row >= M) return;
    int j = t & 127;
    float acc = sb[j];
#pragma unroll
    for (int k = 0; k < F_IN; ++k)
        acc += X[(size_t)row * F_IN + k] * sW[k * H + j];
    out[(size_t)row * H + j] = fmaxf(acc, 0.f);
}

// Gather-encoder: out[p] = relu(X[sortedIds[p],16] @ W + b)  (one-time)
__global__ __launch_bounds__(256) void enc_gather_kernel(const float* __restrict__ X,
                                                         const int* __restrict__ sortedIds,
                                                         const float* __restrict__ W,
                                                         const float* __restrict__ bias,
                                                         float* __restrict__ out, int M)
{
    __shared__ float sW[F_IN * H];
    __shared__ float sb[H];
    int t = threadIdx.x;
    reinterpret_cast<float4*>(sW)[t]       = reinterpret_cast<const float4*>(W)[t];
    reinterpret_cast<float4*>(sW)[t + 256] = reinterpret_cast<const float4*>(W)[t + 256];
    if (t < H) sb[t] = bias[t];
    __syncthreads();
    int p = blockIdx.x * 2 + (t >> 7);
    if (p >= M) return;
    int src = sortedIds[p];
    int j = t & 127;
    float acc = sb[j];
#pragma unroll
    for (int k = 0; k < F_IN; ++k)
        acc += X[(size_t)src * F_IN + k] * sW[k * H + j];
    out[(size_t)p * H + j] = fmaxf(acc, 0.f);
}

// ---------------------------------------------------------------------------
// B-only precompute: B = bn(h)@W2 (raw output).
__global__ __launch_bounds__(256, 4) void bk_kernel(const float* __restrict__ hb,
                                                    const short8* __restrict__ W2p,
                                                    float* __restrict__ Bout, int M,
                                                    const float* __restrict__ bnsums,
                                                    const float* __restrict__ bng,
                                                    const float* __restrict__ bnb,
                                                    float invM)
{
    __shared__ __align__(16) unsigned short sA[64 * 128];
    const int t = threadIdx.x, lane = t & 63, w = t >> 6, jb = 32 * w;
    const int r0 = blockIdx.x * 64;
    stage_bn_bf16(hb, sA, r0, M, t, bnsums, bng, bnb, invM);
    const int g = lane >> 4, c0 = lane & 15;
    short8 wf[4][2];
    load_wfrag(W2p, w, lane, wf);
    f32x4 acc[4][2];
    zero_acc(acc);
    __syncthreads();
    mfma_gemm(sA, wf, acc, lane);
#pragma unroll
    for (int fr = 0; fr < 4; ++fr)
#pragma unroll
        for (int c = 0; c < 2; ++c) {
            int j = jb + 16 * c + c0;
#pragma unroll
            for (int r = 0; r < 4; ++r) {
                int row = r0 + 16 * fr + 4 * g + r;
                if (row < M) Bout[(size_t)row * H + j] = acc[fr][c][r];
            }
        }
}

// ---------------------------------------------------------------------------
// Fused edge kernel over col-sorted e layout:
//   e'[p] = relu(bn(e[p])@W3 + bn(h)[rowS]@W1 + B[colS] + be)
//   m     = relu(e'@U2 + bn(h)[rowS]@U1 + b1)
//   aggsum[col] += segment-reduced m ; fused e'-stats
__global__ __launch_bounds__(256, 4) void edge_kernel(float* eb,
                                                      const int* __restrict__ rowS,
                                                      const int* __restrict__ colS,
                                                      const float* __restrict__ hb,
                                                      const float* __restrict__ Bsrc,
                                                      const short8* __restrict__ W1p,
                                                      const short8* __restrict__ W3p,
                                                      const short8* __restrict__ U1p,
                                                      const short8* __restrict__ U2p,
                                                      const float* __restrict__ be,
                                                      const float* __restrict__ b1,
                                                      float* __restrict__ aggsum, int E,
                                                      const float* __restrict__ bnsumsE,
                                                      const float* __restrict__ bngE,
                                                      const float* __restrict__ bnbE,
                                                      float invE,
                                                      const float* __restrict__ bnsumsH,
                                                      const float* __restrict__ bngH,
                                                      const float* __restrict__ bnbH,
                                                      float invN,
                                                      float* __restrict__ eStats)
{
    __shared__ __align__(16) unsigned char smem[64 * 128 * 4 + 256];
    unsigned short* sE  = (unsigned short*)smem;          // 16 KB  e (bf16)
    unsigned short* sHt = sE + 64 * 128;                  // 16 KB  h[row] (bf16)
    float*          mbuf = (float*)smem;                  // 32 KB overlay (post-GEMM2)
    int*            scol = (int*)(smem + 64 * 128 * 4);   // 256 B

    const int t = threadIdx.x, lane = t & 63, w = t >> 6, jb = 32 * w;
    const int e0 = blockIdx.x * 64;
    const int g = lane >> 4, c0 = lane & 15;

    if (t < 64) scol[t] = colS[(e0 + t < E) ? (e0 + t) : (E - 1)];

    // per-lane col indices + early B prefetch
    int cidx[4][4];
#pragma unroll
    for (int fr = 0; fr < 4; ++fr)
#pragma unroll
        for (int r = 0; r < 4; ++r) {
            int p  = e0 + 16 * fr + 4 * g + r;
            int pc = (p < E) ? p : (E - 1);
            cidx[fr][r] = colS[pc];
        }
    float bPre[4][2][4];
#pragma unroll
    for (int fr = 0; fr < 4; ++fr)
#pragma unroll
        for (int c = 0; c < 2; ++c)
#pragma unroll
            for (int r = 0; r < 4; ++r)
                bPre[fr][c][r] = Bsrc[(size_t)cidx[fr][r] * H + jb + 16 * c + c0];

    // stage e tile (BN_e fused) + gathered h[row] tile (BN_h fused)
    stage_bn_bf16(eb, sE, e0, E, t, bnsumsE, bngE, bnbE, invE);
    stage_bn_bf16_gather(hb, rowS, sHt, e0, E, t, bnsumsH, bngH, bnbH, invN);

    short8 wf[4][2];
    f32x4 acc[4][2];
    zero_acc(acc);
    load_wfrag(W3p, w, lane, wf);
    __syncthreads();
    mfma_gemm(sE, wf, acc, lane);
    load_wfrag(W1p, w, lane, wf);
    mfma_gemm(sHt, wf, acc, lane);
    __syncthreads();   // all reads of sE done -> safe to overwrite with e'

    // epilogue 1: e' = relu(acc + B[col] + be) -> global stream + bf16 back to sE
    float s1[2] = {0.f, 0.f}, s2[2] = {0.f, 0.f};
#pragma unroll
    for (int fr = 0; fr < 4; ++fr)
#pragma unroll
        for (int c = 0; c < 2; ++c) {
            int j = jb + 16 * c + c0;
            float bej = be[j];
#pragma unroll
            for (int r = 0; r < 4; ++r) {
                int Rl = 16 * fr + 4 * g + r;
                int p  = e0 + Rl;
                float v = acc[fr][c][r] + bPre[fr][c][r] + bej;
                v = fmaxf(v, 0.f);
                if (p < E) {
                    eb[(size_t)p * H + j] = v;
                    s1[c] += v;
                    s2[c] += v * v;
                }
                sE[(Rl << 7) + (j ^ ((Rl & 7) << 3))] = f2bf(v);
            }
        }
    __syncthreads();

    // GEMM2: m = e'@U2 + hrow@U1
    zero_acc(acc);
    load_wfrag(U2p, w, lane, wf);
    mfma_gemm(sE, wf, acc, lane);
    load_wfrag(U1p, w, lane, wf);
    mfma_gemm(sHt, wf, acc, lane);
    __syncthreads();   // all GEMM2 LDS reads done -> mbuf overlay safe

    // epilogue 2: m -> mbuf (swizzled)
#pragma unroll
    for (int fr = 0; fr < 4; ++fr)
#pragma unroll
        for (int c = 0; c < 2; ++c) {
            int j = jb + 16 * c + c0;
            float b1j = b1[j];
#pragma unroll
            for (int r = 0; r < 4; ++r) {
                int Rl = 16 * fr + 4 * g + r;
                float v = fmaxf(acc[fr][c][r] + b1j, 0.f);
                mbuf[(Rl << 7) + (j ^ (((Rl >> 2) & 3) << 3))] = v;
            }
        }
    __syncthreads();

    // segmented reduction: thread j walks 64 sorted rows, 1 atomic per segment
    if (t < 128) {
        int j = t;
        float run = 0.f;
        int cur = scol[0];
        for (int row = 0; row < 64; ++row) {
            int cc = scol[row];
            float v = mbuf[(row << 7) + (j ^ (((row >> 2) & 3) << 3))];
            if (cc != cur) {
                atomicAdd(&aggsum[(size_t)cur * H + j], run);
                run = 0.f;
                cur = cc;
            }
            if (e0 + row < E) run += v;
        }
        atomicAdd(&aggsum[(size_t)cur * H + j], run);
    }

    // fused e'-stats
#pragma unroll
    for (int c = 0; c < 2; ++c) {
        float a = s1[c], b = s2[c];
        a += __shfl_xor(a, 16); a += __shfl_xor(a, 32);
        b += __shfl_xor(b, 16); b += __shfl_xor(b, 32);
        if (g == 0) {
            int j = jb + 16 * c + c0;
            atomicAdd(&eStats[j], a);
            atomicAdd(&eStats[H + j], b);
        }
    }
}

// ---------------------------------------------------------------------------
// Node update (in place): h = relu(bn(h)@V1 + (aggsum/max(cnt,1))@V2 + b2)
// fused h-stats
__global__ __launch_bounds__(256, 4) void node_kernel(float* hb,
                                                      const float* __restrict__ aggsum,
                                                      const int* __restrict__ cnt,
                                                      const short8* __restrict__ V1p,
                                                      const short8* __restrict__ V2p,
                                                      const float* __restrict__ b2, int M,
                                                      const float* __restrict__ bnsums,
                                                      const float* __restrict__ bng,
                                                      const float* __restrict__ bnb,
                                                      float invM,
                                                      float* __restrict__ hStats)
{
    __shared__ __align__(16) unsigned short sA[64 * 128];
    const int t = threadIdx.x, lane = t & 63, w = t >> 6, jb = 32 * w;
    const int r0 = blockIdx.x * 64;
    stage_bn_bf16(hb, sA, r0, M, t, bnsums, bng, bnb, invM);
    short8 wf[4][2];
    load_wfrag(V1p, w, lane, wf);
    f32x4 acc[4][2];
    zero_acc(acc);
    __syncthreads();
    mfma_gemm(sA, wf, acc, lane);
    __syncthreads();   // h-tile reads done
    stage_agg_bf16(aggsum, cnt, sA, r0, M, t);
    load_wfrag(V2p, w, lane, wf);
    __syncthreads();
    mfma_gemm(sA, wf, acc, lane);
    const int g = lane >> 4, c0 = lane & 15;
    float s1[2] = {0.f, 0.f}, s2[2] = {0.f, 0.f};
#pragma unroll
    for (int fr = 0; fr < 4; ++fr)
#pragma unroll
        for (int c = 0; c < 2; ++c) {
            int j = jb + 16 * c + c0;
            float bj = b2[j];
#pragma unroll
            for (int r = 0; r < 4; ++r) {
                int row = r0 + 16 * fr + 4 * g + r;
                if (row < M) {
                    float v = fmaxf(acc[fr][c][r] + bj, 0.f);
                    hb[(size_t)row * H + j] = v;
                    s1[c] += v;
                    s2[c] += v * v;
                }
            }
        }
#pragma unroll
    for (int c = 0; c < 2; ++c) {
        float a = s1[c], b = s2[c];
        a += __shfl_xor(a, 16); a += __shfl_xor(a, 32);
        b += __shfl_xor(b, 16); b += __shfl_xor(b, 32);
        if (g == 0) {
            int j = jb + 16 * c + c0;
            atomicAdd(&hStats[j], a);
            atomicAdd(&hStats[H + j], b);
        }
    }
}

// ---------------------------------------------------------------------------
// Final readout: out = [mean(h) | mean(e)] @ reg_w + reg_b
__global__ __launch_bounds__(256) void final_kernel(const float* __restrict__ hsum,
                                                    const float* __restrict__ esum,
                                                    const float* __restrict__ reg_w,
                                                    const float* __restrict__ reg_b,
                                                    float* __restrict__ out,
                                                    float invN, float invE)
{
    __shared__ float red[256];
    int t = threadIdx.x;
    float v = (t < 128) ? hsum[t] * invN * reg_w[t]
                        : esum[t - 128] * invE * reg_w[t];
    red[t] = v;
    __syncthreads();
    for (int s = 128; s > 0; s >>= 1) {
        if (t < s) red[t] += red[t + s];
        __syncthreads();
    }
    if (t == 0) out[0] = red[0] + reg_b[0];
}

// ---------------------------------------------------------------------------
extern "C" void kernel_launch(void* const* d_in, const int* in_sizes, int n_in,
                              void* d_out, int out_size, void* d_ws, size_t ws_size,
                              hipStream_t stream)
{
    const float* x          = (const float*)d_in[0];
    const int*   edge_index = (const int*)  d_in[1];
    const float* edge_attr  = (const float*)d_in[2];
    const float* enc_node_w = (const float*)d_in[3];
    const float* enc_node_b = (const float*)d_in[4];
    const float* enc_edge_w = (const float*)d_in[5];
    const float* enc_edge_b = (const float*)d_in[6];
    const float* edge_w     = (const float*)d_in[7];
    const float* edge_b     = (const float*)d_in[8];
    const float* n1_w       = (const float*)d_in[9];
    const float* n1_b       = (const float*)d_in[10];
    const float* n2_w       = (const float*)d_in[11];
    const float* n2_b       = (const float*)d_in[12];
    const float* bn_node_g  = (const float*)d_in[13];
    const float* bn_node_b  = (const float*)d_in[14];
    const float* bn_edge_g  = (const float*)d_in[15];
    const float* bn_edge_b  = (const float*)d_in[16];
    const float* reg_w      = (const float*)d_in[17];
    const float* reg_b      = (const float*)d_in[18];

    const int N = in_sizes[0] / F_IN;
    const int E = in_sizes[1] / 2;
    const size_t NH = (size_t)N * H;
    const size_t EH = (size_t)E * H;

    float* ws     = (float*)d_ws;
    float* hbuf   = ws;                 // [N,128]
    float* ebuf   = hbuf + NH;          // [E,128]  (stored in col-sorted order)
    float* Bbuf   = ebuf + EH;          // [N,128]
    float* aggsum = Bbuf + NH;          // [N,128]
    float* statsA = aggsum + NH;        // 512
    float* statsB = statsA + 512;       // 512
    short8* wfr   = (short8*)(statsB + 512);        // 21 * 2048 short8 = 672 KB
    float* afterW = (float*)(wfr + 21 * 2048);
    int*   cnt_i  = (int*)afterW;           // [N]
    int*   tmpc   = cnt_i + N;              // [N]
    int*   offs   = tmpc + N;               // [N+1]
    int*   sortedIds = offs + N + 1;        // [E]
    int*   rowS   = sortedIds + E;          // [E]
    int*   colS   = rowS + E;               // [E]

    const int* row_idx = edge_index;
    const int* col_idx = edge_index + E;
    const float invN = 1.f / (float)N;
    const float invE = 1.f / (float)E;

    // one-time: sort edges by col, build permuted index arrays; bf16 weights
    (void)hipMemsetAsync(cnt_i, 0, (size_t)2 * N * sizeof(int), stream);
    hist_kernel<<<(E + 255) / 256, 256, 0, stream>>>(col_idx, cnt_i, E);
    scan_kernel<<<1, 1024, 0, stream>>>(cnt_i, offs, N);
    scatter_kernel<<<(E + 255) / 256, 256, 0, stream>>>(row_idx, col_idx, offs, tmpc,
                                                        sortedIds, rowS, colS, E);
    wbf16_kernel<<<21, 256, 0, stream>>>(edge_w, n1_w, n2_w, wfr);

    enc_kernel<<<(N + 1) / 2, 256, 0, stream>>>(x, enc_node_w, enc_node_b, hbuf, N);
    enc_gather_kernel<<<(E + 1) / 2, 256, 0, stream>>>(edge_attr, sortedIds,
                                                       enc_edge_w, enc_edge_b, ebuf, E);

    const int nodeBlocks = (N + 63) / 64;
    const int edgeBlocks = (E + 63) / 64;

    for (int i = 0; i < 3; ++i) {
        float*       Scur  = (i & 1) ? statsB : statsA;
        const float* Sprev = (i == 0) ? nullptr : ((i & 1) ? statsA : statsB);
        const short8* W1p = wfr + (size_t)(i * 7 + 0) * 2048;
        const short8* W2p = wfr + (size_t)(i * 7 + 1) * 2048;
        const short8* W3p = wfr + (size_t)(i * 7 + 2) * 2048;
        const short8* U1p = wfr + (size_t)(i * 7 + 3) * 2048;
        const short8* U2p = wfr + (size_t)(i * 7 + 4) * 2048;
        const short8* V1p = wfr + (size_t)(i * 7 + 5) * 2048;
        const short8* V2p = wfr + (size_t)(i * 7 + 6) * 2048;
        (void)hipMemsetAsync(aggsum, 0, NH * sizeof(float), stream);
        (void)hipMemsetAsync(Scur, 0, 512 * sizeof(float), stream);
        bk_kernel<<<nodeBlocks, 256, 0, stream>>>(
            hbuf, W2p, Bbuf, N, Sprev, bn_node_g, bn_node_b, invN);
        edge_kernel<<<edgeBlocks, 256, 0, stream>>>(
            ebuf, rowS, colS, hbuf, Bbuf,
            W1p, W3p, U1p, U2p,
            edge_b + i * H, n1_b + i * H,
            aggsum, E,
            Sprev ? Sprev + 256 : nullptr, bn_edge_g, bn_edge_b, invE,
            Sprev, bn_node_g, bn_node_b, invN,
            Scur + 256);
        node_kernel<<<nodeBlocks, 256, 0, stream>>>(
            hbuf, aggsum, cnt_i, V1p, V2p, n2_b + i * H, N,
            Sprev, bn_node_g, bn_node_b, invN,
            Scur);
    }
    // i=2 wrote statsA
    final_kernel<<<1, 256, 0, stream>>>(statsA, statsA + 256, reg_w, reg_b,
                                        (float*)d_out, invN, invE);
}